// Round 1
// baseline (2606.088 us; speedup 1.0000x reference)
//
#include <hip/hip_runtime.h>
#include <hip/hip_bf16.h>
#include <cstddef>

// Problem constants (Qwen3-style attention block, fp32)
constexpr int B_   = 2;
constexpr int S_   = 2048;
constexpr int D_   = 2048;
constexpr int H_   = 16;
constexpr int HKV_ = 4;
constexpr int HD_  = 128;
constexpr int M_   = B_ * S_;        // 4096 token rows
constexpr int NQ_  = H_ * HD_;       // 2048
constexpr int NKV_ = HKV_ * HD_;     // 512
constexpr float QSCALE = 0.08838834764831845f;  // 1/sqrt(128)

// ---------------------------------------------------------------------------
// Generic fp32 GEMM: C[M,N] = A[M,K] * B[K,N], all row-major.
// 128x128 block, BK=16, 256 threads, 8x8 per thread as 2x2 blocks of 4x4
// (the 4tx / 64+4tx split keeps LDS reads at the b128 bank floor).
// ---------------------------------------------------------------------------
__global__ __launch_bounds__(256, 2) void gemm_f32(
    const float* __restrict__ A, const float* __restrict__ Bm,
    float* __restrict__ C, int M, int N, int K)
{
  __shared__ float asT[16][128];   // asT[kk][m] = A[bm+m][k0+kk]
  __shared__ float bs[16][132];    // bs[kk][n]  = B[k0+kk][bn+n] (pad keeps write at floor)

  const int t  = threadIdx.x;
  const int tx = t & 15, ty = t >> 4;
  const int bm = blockIdx.y * 128, bn = blockIdx.x * 128;

  float acc[2][2][4][4];
  #pragma unroll
  for (int a = 0; a < 2; ++a)
    #pragma unroll
    for (int b = 0; b < 2; ++b)
      #pragma unroll
      for (int i = 0; i < 4; ++i)
        #pragma unroll
        for (int j = 0; j < 4; ++j) acc[a][b][i][j] = 0.f;

  const float* Ap = A + (size_t)(bm + (t >> 1)) * K + (t & 1) * 8;
  const float* Bp = Bm + (size_t)(t >> 4) * N + bn + (t & 15) * 8;

  for (int k0 = 0; k0 < K; k0 += 16) {
    const float4 a0 = *(const float4*)(Ap);
    const float4 a1 = *(const float4*)(Ap + 4);
    const float4 b0 = *(const float4*)(Bp);
    const float4 b1 = *(const float4*)(Bp + 4);
    __syncthreads();   // previous iteration's LDS reads complete
    {
      const int kk = (t & 1) * 8, m = t >> 1;
      asT[kk + 0][m] = a0.x; asT[kk + 1][m] = a0.y;
      asT[kk + 2][m] = a0.z; asT[kk + 3][m] = a0.w;
      asT[kk + 4][m] = a1.x; asT[kk + 5][m] = a1.y;
      asT[kk + 6][m] = a1.z; asT[kk + 7][m] = a1.w;
      *(float4*)&bs[t >> 4][(t & 15) * 8]     = b0;
      *(float4*)&bs[t >> 4][(t & 15) * 8 + 4] = b1;
    }
    __syncthreads();

    #pragma unroll
    for (int kk = 0; kk < 16; ++kk) {
      const float4 av0 = *(const float4*)&asT[kk][4 * ty];
      const float4 av1 = *(const float4*)&asT[kk][64 + 4 * ty];
      const float4 bv0 = *(const float4*)&bs[kk][4 * tx];
      const float4 bv1 = *(const float4*)&bs[kk][64 + 4 * tx];
      const float ar[2][4] = {{av0.x, av0.y, av0.z, av0.w},
                              {av1.x, av1.y, av1.z, av1.w}};
      const float br[2][4] = {{bv0.x, bv0.y, bv0.z, bv0.w},
                              {bv1.x, bv1.y, bv1.z, bv1.w}};
      #pragma unroll
      for (int rb = 0; rb < 2; ++rb)
        #pragma unroll
        for (int i = 0; i < 4; ++i)
          #pragma unroll
          for (int cb = 0; cb < 2; ++cb)
            #pragma unroll
            for (int j = 0; j < 4; ++j)
              acc[rb][cb][i][j] = fmaf(ar[rb][i], br[cb][j], acc[rb][cb][i][j]);
    }
    Ap += 16;
    Bp += (size_t)16 * N;
  }

  #pragma unroll
  for (int rb = 0; rb < 2; ++rb)
    #pragma unroll
    for (int i = 0; i < 4; ++i) {
      float* crow = C + (size_t)(bm + rb * 64 + 4 * ty + i) * N + bn;
      #pragma unroll
      for (int cb = 0; cb < 2; ++cb) {
        const float4 o = make_float4(acc[rb][cb][i][0], acc[rb][cb][i][1],
                                     acc[rb][cb][i][2], acc[rb][cb][i][3]);
        *(float4*)(crow + cb * 64 + 4 * tx) = o;
      }
    }
}

// ---------------------------------------------------------------------------
// Fused RMSNorm (over HD=128) + RoPE, in place on q_proj / k_proj.
// One 64-thread wave per head-row; thread i owns the rope pair (i, i+64).
// ---------------------------------------------------------------------------
__global__ __launch_bounds__(64) void rmsrope(
    float* __restrict__ qp, float* __restrict__ kp,
    const float* __restrict__ qw, const float* __restrict__ kw,
    const int* __restrict__ pos_ids)
{
  const int row  = blockIdx.x;
  const int lane = threadIdx.x;
  constexpr int NQROWS = M_ * H_;

  float* ptr; const float* w; int bs_;
  if (row < NQROWS) {
    ptr = qp + (size_t)row * HD_;  w = qw;  bs_ = row / H_;
  } else {
    const int rk = row - NQROWS;
    ptr = kp + (size_t)rk * HD_;   w = kw;  bs_ = rk / HKV_;
  }

  const float x1 = ptr[lane];
  const float x2 = ptr[lane + 64];
  float ss = x1 * x1 + x2 * x2;
  #pragma unroll
  for (int m = 1; m < 64; m <<= 1) ss += __shfl_xor(ss, m, 64);
  const float rinv = rsqrtf(ss * (1.0f / 128.0f) + 1e-6f);
  const float y1 = x1 * rinv * w[lane];
  const float y2 = x2 * rinv * w[lane + 64];

  const int pos = pos_ids[bs_];
  const float f = (float)pos * powf(10000.0f, -(float)lane * (1.0f / 64.0f));
  float sn, c;
  sincosf(f, &sn, &c);
  ptr[lane]      = y1 * c - y2 * sn;
  ptr[lane + 64] = y2 * c + y1 * sn;
}

// ---------------------------------------------------------------------------
// Causal GQA flash attention, fp32. One block per (64-row Q tile, b, h).
// Q/K stored transposed in LDS ([d][r], [d][j]) for conflict-free b128 reads;
// scores + online softmax live in registers (16-lane shuffle reductions);
// P goes through LDS; V is chunk-rotated in LDS to hit the b128 write floor.
// LDS = 32+32+16 KB = 80 KB -> 2 blocks/CU.
// ---------------------------------------------------------------------------
__global__ __launch_bounds__(256, 2) void attn(
    const float* __restrict__ qp, const float* __restrict__ kp,
    const float* __restrict__ vp, float* __restrict__ op)
{
  __shared__ float qT[128][64];    // qT[d][r], pre-scaled by 1/sqrt(HD)
  __shared__ float kv[64 * 128];   // K phase: kv[d*64+j]; V phase: kv[j*128 + rot]
  __shared__ float sP[64][64];     // P[r][j]

  const int t  = threadIdx.x;
  const int tx = t & 15, ty = t >> 4;
  const int qt = blockIdx.x;
  const int bh = blockIdx.y;
  const int b   = bh / H_;
  const int h   = bh % H_;
  const int kvh = h / (H_ / HKV_);
  const int q0  = qt * 64;

  // ---- stage Q tile (transposed, scaled) ----
  {
    const int r  = t >> 2;
    const int d0 = (t & 3) * 4;
    const float* qrow = qp + ((size_t)(b * S_ + q0 + r) * H_ + h) * HD_;
    #pragma unroll
    for (int rep = 0; rep < 8; ++rep) {
      const int d = d0 + rep * 16;
      const float4 v4 = *(const float4*)(qrow + d);
      qT[d + 0][r] = v4.x * QSCALE;
      qT[d + 1][r] = v4.y * QSCALE;
      qT[d + 2][r] = v4.z * QSCALE;
      qT[d + 3][r] = v4.w * QSCALE;
    }
  }

  float o_acc[2][4][4];   // [cb][i][cc]; c = cb*64 + 4*tx + cc, r = 4*ty + i
  #pragma unroll
  for (int cb = 0; cb < 2; ++cb)
    #pragma unroll
    for (int i = 0; i < 4; ++i)
      #pragma unroll
      for (int cc = 0; cc < 4; ++cc) o_acc[cb][i][cc] = 0.f;
  float m_i[4], l_i[4];
  #pragma unroll
  for (int i = 0; i < 4; ++i) { m_i[i] = -1e30f; l_i[i] = 0.f; }

  const int jload  = t >> 2;                       // K-stage row
  const int dload0 = (t & 3) * 4;
  const int vj     = ((t & 63) >> 2) + 16 * (t >> 6);  // V-stage row

  for (int kt = 0; kt <= qt; ++kt) {
    const int k0 = kt * 64;
    __syncthreads();   // previous PV done with kv + sP
    // ---- stage K (transposed) ----
    {
      const float* krow = kp + (size_t)(b * S_ + k0 + jload) * NKV_ + kvh * HD_;
      #pragma unroll
      for (int rep = 0; rep < 8; ++rep) {
        const int d = dload0 + rep * 16;
        const float4 v4 = *(const float4*)(krow + d);
        kv[(d + 0) * 64 + jload] = v4.x;
        kv[(d + 1) * 64 + jload] = v4.y;
        kv[(d + 2) * 64 + jload] = v4.z;
        kv[(d + 3) * 64 + jload] = v4.w;
      }
    }
    __syncthreads();

    // ---- scores: s[r][j] = (q/sqrt(HD)) . k ----
    float s_reg[4][4];
    #pragma unroll
    for (int i = 0; i < 4; ++i)
      #pragma unroll
      for (int jj = 0; jj < 4; ++jj) s_reg[i][jj] = 0.f;

    #pragma unroll 8
    for (int d = 0; d < 128; ++d) {
      const float4 a4 = *(const float4*)&qT[d][4 * ty];
      const float4 b4 = *(const float4*)&kv[d * 64 + 4 * tx];
      const float aq[4] = {a4.x, a4.y, a4.z, a4.w};
      const float bk[4] = {b4.x, b4.y, b4.z, b4.w};
      #pragma unroll
      for (int i = 0; i < 4; ++i)
        #pragma unroll
        for (int jj = 0; jj < 4; ++jj)
          s_reg[i][jj] = fmaf(aq[i], bk[jj], s_reg[i][jj]);
    }

    if (kt == qt) {  // causal mask on the diagonal tile
      #pragma unroll
      for (int i = 0; i < 4; ++i)
        #pragma unroll
        for (int jj = 0; jj < 4; ++jj)
          if (4 * tx + jj > 4 * ty + i) s_reg[i][jj] = -1e30f;
    }

    // ---- online softmax (registers + 16-lane shuffles) ----
    #pragma unroll
    for (int i = 0; i < 4; ++i) {
      float rm = fmaxf(fmaxf(s_reg[i][0], s_reg[i][1]),
                       fmaxf(s_reg[i][2], s_reg[i][3]));
      #pragma unroll
      for (int msk = 1; msk < 16; msk <<= 1) rm = fmaxf(rm, __shfl_xor(rm, msk, 64));
      const float mn    = fmaxf(m_i[i], rm);
      const float alpha = __expf(m_i[i] - mn);
      float ps = 0.f;
      #pragma unroll
      for (int jj = 0; jj < 4; ++jj) {
        const float p = __expf(s_reg[i][jj] - mn);
        s_reg[i][jj] = p;
        ps += p;
      }
      #pragma unroll
      for (int msk = 1; msk < 16; msk <<= 1) ps += __shfl_xor(ps, msk, 64);
      l_i[i] = l_i[i] * alpha + ps;
      m_i[i] = mn;
      #pragma unroll
      for (int cb = 0; cb < 2; ++cb)
        #pragma unroll
        for (int cc = 0; cc < 4; ++cc) o_acc[cb][i][cc] *= alpha;
    }

    // ---- P -> LDS ----
    #pragma unroll
    for (int i = 0; i < 4; ++i)
      *(float4*)&sP[4 * ty + i][4 * tx] =
          make_float4(s_reg[i][0], s_reg[i][1], s_reg[i][2], s_reg[i][3]);
    __syncthreads();   // K reads + P writes complete

    // ---- stage V (chunk-rotated rows) ----
    {
      const float* vrow = vp + (size_t)(b * S_ + k0 + vj) * NKV_ + kvh * HD_;
      #pragma unroll
      for (int rep = 0; rep < 8; ++rep) {
        const int d = dload0 + rep * 16;
        const float4 v4 = *(const float4*)(vrow + d);
        const int ch = (((d >> 2) + vj) & 31) << 2;
        *(float4*)&kv[vj * 128 + ch] = v4;
      }
    }
    __syncthreads();

    // ---- PV accumulate ----
    #pragma unroll 2
    for (int j0 = 0; j0 < 64; j0 += 4) {
      float pf[4][4];
      #pragma unroll
      for (int i = 0; i < 4; ++i)
        *(float4*)pf[i] = *(const float4*)&sP[4 * ty + i][j0];
      #pragma unroll
      for (int jj = 0; jj < 4; ++jj) {
        const int j = j0 + jj;
        const float4 v0 = *(const float4*)&kv[j * 128 + (((tx + j) & 31) << 2)];
        const float4 v1 = *(const float4*)&kv[j * 128 + (((tx + 16 + j) & 31) << 2)];
        const float vr[2][4] = {{v0.x, v0.y, v0.z, v0.w},
                                {v1.x, v1.y, v1.z, v1.w}};
        #pragma unroll
        for (int i = 0; i < 4; ++i) {
          const float p = pf[i][jj];
          #pragma unroll
          for (int cc = 0; cc < 4; ++cc) {
            o_acc[0][i][cc] = fmaf(p, vr[0][cc], o_acc[0][i][cc]);
            o_acc[1][i][cc] = fmaf(p, vr[1][cc], o_acc[1][i][cc]);
          }
        }
      }
    }
  }

  // ---- normalize + write (B,S,H,HD) so WO GEMM reads contiguous rows ----
  #pragma unroll
  for (int i = 0; i < 4; ++i) {
    const float inv = 1.0f / l_i[i];
    float* orow = op + ((size_t)(b * S_ + q0 + 4 * ty + i) * H_ + h) * HD_;
    const float4 w0 = make_float4(o_acc[0][i][0] * inv, o_acc[0][i][1] * inv,
                                  o_acc[0][i][2] * inv, o_acc[0][i][3] * inv);
    const float4 w1 = make_float4(o_acc[1][i][0] * inv, o_acc[1][i][1] * inv,
                                  o_acc[1][i][2] * inv, o_acc[1][i][3] * inv);
    *(float4*)(orow + 4 * tx)      = w0;
    *(float4*)(orow + 64 + 4 * tx) = w1;
  }
}

// ---------------------------------------------------------------------------
extern "C" void kernel_launch(void* const* d_in, const int* in_sizes, int n_in,
                              void* d_out, int out_size, void* d_ws, size_t ws_size,
                              hipStream_t stream) {
  const float* hidden = (const float*)d_in[0];
  const float* wq     = (const float*)d_in[1];
  const float* wk     = (const float*)d_in[2];
  const float* wv     = (const float*)d_in[3];
  const float* wo     = (const float*)d_in[4];
  const float* qw     = (const float*)d_in[5];
  const float* kw     = (const float*)d_in[6];
  const int*   pos    = (const int*)d_in[7];
  float*       out    = (float*)d_out;

  // Workspace layout (floats): q_proj | k_proj | v_proj | attn_out
  const size_t q_elems  = (size_t)M_ * NQ_;    // 8388608
  const size_t kv_elems = (size_t)M_ * NKV_;   // 2097152
  const size_t needed   = (q_elems * 2 + kv_elems * 2) * sizeof(float); // ~84 MB
  if (ws_size < needed) return;  // leaves d_out poisoned -> visible failure

  float* q_proj = (float*)d_ws;
  float* k_proj = q_proj + q_elems;
  float* v_proj = k_proj + kv_elems;
  float* attn_o = v_proj + kv_elems;

  // 1) projections
  gemm_f32<<<dim3(NQ_ / 128, M_ / 128), 256, 0, stream>>>(hidden, wq, q_proj, M_, NQ_, D_);
  gemm_f32<<<dim3(NKV_ / 128, M_ / 128), 256, 0, stream>>>(hidden, wk, k_proj, M_, NKV_, D_);
  gemm_f32<<<dim3(NKV_ / 128, M_ / 128), 256, 0, stream>>>(hidden, wv, v_proj, M_, NKV_, D_);

  // 2) RMSNorm + RoPE in place on q_proj / k_proj
  rmsrope<<<M_ * (H_ + HKV_), 64, 0, stream>>>(q_proj, k_proj, qw, kw, pos);

  // 3) causal GQA attention -> attn_o in (B,S,H,HD)
  attn<<<dim3(S_ / 64, B_ * H_), 256, 0, stream>>>(q_proj, k_proj, v_proj, attn_o);

  // 4) output projection
  gemm_f32<<<dim3(D_ / 128, M_ / 128), 256, 0, stream>>>(attn_o, wo, out, M_, D_, D_);
}

// Round 2
// 1538.124 us; speedup vs baseline: 1.6943x; 1.6943x over previous
//
#include <hip/hip_runtime.h>
#include <hip/hip_bf16.h>
#include <cstddef>

// Problem constants (Qwen3-style attention block, fp32 in/out)
constexpr int B_   = 2;
constexpr int S_   = 2048;
constexpr int D_   = 2048;
constexpr int H_   = 16;
constexpr int HKV_ = 4;
constexpr int HD_  = 128;
constexpr int M_   = B_ * S_;        // 4096 token rows
constexpr int NQKV_ = H_ * HD_ + 2 * HKV_ * HD_;  // 3072 fused QKV cols
constexpr float QSCALE = 0.08838834764831845f;    // 1/sqrt(128)

typedef __attribute__((ext_vector_type(8))) short bs8;   // 8 bf16 (4 VGPR)
typedef __attribute__((ext_vector_type(4))) float fx4;   // MFMA accumulator

// ---------------------------------------------------------------------------
// helpers
// ---------------------------------------------------------------------------
__device__ __forceinline__ void split2(float x, short& hi, short& lo) {
  __hip_bfloat16 h = __float2bfloat16(x);          // RNE
  float hf = __bfloat162float(h);
  __hip_bfloat16 l = __float2bfloat16(x - hf);
  hi = *(short*)&h;
  lo = *(short*)&l;
}

__device__ __forceinline__ void gload16(const short* g, short* l) {
  __builtin_amdgcn_global_load_lds(
      (const __attribute__((address_space(1))) void*)g,
      (__attribute__((address_space(3))) void*)l, 16, 0, 0);
}

// ---------------------------------------------------------------------------
// Split hidden (M x 2048 fp32) -> Asp (M x 4096 bf16, cols [0,2048)=hi, [2048,4096)=lo)
// ---------------------------------------------------------------------------
__global__ __launch_bounds__(256) void split_hidden(
    const float4* __restrict__ X, short* __restrict__ out)
{
  const long i4  = (long)blockIdx.x * 256 + threadIdx.x;  // M*2048/4 float4s
  const long row = i4 >> 9;                               // 512 float4 per row
  const long c   = (i4 & 511) * 4;
  const float4 v = X[i4];
  short h[4], l[4];
  split2(v.x, h[0], l[0]); split2(v.y, h[1], l[1]);
  split2(v.z, h[2], l[2]); split2(v.w, h[3], l[3]);
  *(short4*)&out[row * 4096 + c]        = make_short4(h[0], h[1], h[2], h[3]);
  *(short4*)&out[row * 4096 + 2048 + c] = make_short4(l[0], l[1], l[2], l[3]);
}

// ---------------------------------------------------------------------------
// Transpose+split a weight W (2048 x N fp32, row-major) into
// out[(row0+n)*4096 + k] = hi(W[k][n]), out[(row0+n)*4096 + 2048 + k] = lo.
// block (32,8), 32x32 tiles through LDS.
// ---------------------------------------------------------------------------
__global__ __launch_bounds__(256) void tsplit(
    const float* __restrict__ W, int N, short* __restrict__ out, int row0)
{
  __shared__ float tile[32][33];
  const int k0 = blockIdx.y * 32;
  const int n0 = blockIdx.x * 32;
  const int x = threadIdx.x, y = threadIdx.y;
  #pragma unroll
  for (int i = 0; i < 4; ++i)
    tile[y + 8 * i][x] = W[(size_t)(k0 + y + 8 * i) * N + n0 + x];
  __syncthreads();
  #pragma unroll
  for (int i = 0; i < 4; ++i) {
    const int n = n0 + y + 8 * i;
    const float v = tile[x][y + 8 * i];
    short hi, lo;
    split2(v, hi, lo);
    out[(size_t)(row0 + n) * 4096 + k0 + x]        = hi;
    out[(size_t)(row0 + n) * 4096 + 2048 + k0 + x] = lo;
  }
}

// ---------------------------------------------------------------------------
// Split-bf16 MFMA GEMM (m97 structure): C[M,N] fp32 = A * B with
//   Asp: M x 2K bf16 row-major, cols [0,K)=hi, [K,2K)=lo
//   Bsp: N x 2K bf16 row-major (B^T), same hi/lo split
// Virtual K' = 3K: seg0 = hi*hi, seg1 = lo*hi, seg2 = hi*lo.
// 128x128 tile, 4 waves (2x2), 4x4 16x16x32-MFMA frags per wave.
// ---------------------------------------------------------------------------
__global__ __launch_bounds__(256, 2) void gemm_split_bf16(
    const short* __restrict__ Asp, const short* __restrict__ Bsp,
    float* __restrict__ C, int M, int N, int K)
{
  __shared__ short As[128 * 32];
  __shared__ short Bs[128 * 32];

  const int t    = threadIdx.x;
  const int lane = t & 63, wid = t >> 6;
  const int wr   = wid >> 1, wc = wid & 1;
  const int bm   = blockIdx.y * 128, bn = blockIdx.x * 128;
  const int ld   = 2 * K;

  fx4 acc[4][4] = {};

  // staging: thread t loads 16B chunks t and t+256 of each 8KB tile
  const int sr = t >> 2;          // row 0..63 (and +64 for 2nd chunk)
  const int sk = (t & 3) * 8;     // k element offset within 32
  short* lA  = As + t * 8;
  short* lA2 = As + (t + 256) * 8;
  short* lB  = Bs + t * 8;
  short* lB2 = Bs + (t + 256) * 8;
  const short* gA = Asp + (size_t)(bm + sr) * ld + sk;
  const short* gB = Bsp + (size_t)(bn + sr) * ld + sk;
  const size_t rstep = (size_t)64 * ld;

  const int lr = lane & 15, lk = (lane >> 4) * 8;

  for (int kp = 0; kp < 3 * K; kp += 32) {
    const int ca = (kp < 2 * K) ? kp : kp - 2 * K;  // A col base (hi|lo|hi)
    const int cb = (kp < K) ? kp : kp - K;          // B col base (hi|hi|lo)
    gload16(gA + ca, lA);
    gload16(gA + ca + rstep, lA2);
    gload16(gB + cb, lB);
    gload16(gB + cb + rstep, lB2);
    __syncthreads();   // drains vmcnt -> LDS tiles ready

    bs8 af[4], bf[4];
    #pragma unroll
    for (int m = 0; m < 4; ++m)
      af[m] = *(const bs8*)&As[(wr * 64 + m * 16 + lr) * 32 + lk];
    #pragma unroll
    for (int n = 0; n < 4; ++n)
      bf[n] = *(const bs8*)&Bs[(wc * 64 + n * 16 + lr) * 32 + lk];
    #pragma unroll
    for (int m = 0; m < 4; ++m)
      #pragma unroll
      for (int n = 0; n < 4; ++n)
        acc[m][n] = __builtin_amdgcn_mfma_f32_16x16x32_bf16(af[m], bf[n], acc[m][n], 0, 0, 0);
    __syncthreads();   // all frag reads done before next stage overwrites
  }

  // epilogue: C/D mapping col=lane&15, row=(lane>>4)*4+reg (m89-verified)
  const int lg = lane >> 4;
  #pragma unroll
  for (int m = 0; m < 4; ++m)
    #pragma unroll
    for (int n = 0; n < 4; ++n) {
      const int col = bn + wc * 64 + n * 16 + lr;
      #pragma unroll
      for (int r = 0; r < 4; ++r) {
        const int row = bm + wr * 64 + m * 16 + lg * 4 + r;
        C[(size_t)row * N + col] = acc[m][n][r];
      }
    }
}

// ---------------------------------------------------------------------------
// Fused RMSNorm (over HD=128) + RoPE, in place on the fused qkv buffer.
// qkv row layout: [q: 16*128 | k: 4*128 | v: 4*128], row stride 3072.
// ---------------------------------------------------------------------------
__global__ __launch_bounds__(64) void rmsrope(
    float* __restrict__ qkv, const float* __restrict__ qw,
    const float* __restrict__ kw, const int* __restrict__ pos_ids)
{
  const int row  = blockIdx.x;
  const int lane = threadIdx.x;
  constexpr int NQROWS = M_ * H_;

  float* ptr; const float* w; int token;
  if (row < NQROWS) {
    token = row / H_;
    ptr = qkv + (size_t)token * NQKV_ + (row % H_) * HD_;
    w = qw;
  } else {
    const int rk = row - NQROWS;
    token = rk / HKV_;
    ptr = qkv + (size_t)token * NQKV_ + 2048 + (rk % HKV_) * HD_;
    w = kw;
  }

  const float x1 = ptr[lane];
  const float x2 = ptr[lane + 64];
  float ss = x1 * x1 + x2 * x2;
  #pragma unroll
  for (int m = 1; m < 64; m <<= 1) ss += __shfl_xor(ss, m, 64);
  const float rinv = rsqrtf(ss * (1.0f / 128.0f) + 1e-6f);
  const float y1 = x1 * rinv * w[lane];
  const float y2 = x2 * rinv * w[lane + 64];

  const int pos = pos_ids[token];
  const float f = (float)pos * powf(10000.0f, -(float)lane * (1.0f / 64.0f));
  float sn, c;
  sincosf(f, &sn, &c);
  ptr[lane]      = y1 * c - y2 * sn;
  ptr[lane + 64] = y2 * c + y1 * sn;
}

// ---------------------------------------------------------------------------
// Causal GQA flash attention, fp32 (unchanged internals from round 1).
// Reads fused qkv; epilogue writes hi/lo bf16 split rows for the WO GEMM:
//   osp[row][h*128+d] = hi, osp[row][2048 + h*128+d] = lo   (row-major, ld 4096)
// ---------------------------------------------------------------------------
__global__ __launch_bounds__(256, 2) void attn(
    const float* __restrict__ qkv, short* __restrict__ osp)
{
  __shared__ float qT[128][64];    // qT[d][r], pre-scaled
  __shared__ float kv[64 * 128];   // K phase: kv[d*64+j]; V phase: rotated rows
  __shared__ float sP[64][64];

  const int t  = threadIdx.x;
  const int tx = t & 15, ty = t >> 4;
  const int qt = blockIdx.x;
  const int bh = blockIdx.y;
  const int b   = bh / H_;
  const int h   = bh % H_;
  const int kvh = h / (H_ / HKV_);
  const int q0  = qt * 64;

  {
    const int r  = t >> 2;
    const int d0 = (t & 3) * 4;
    const float* qrow = qkv + (size_t)(b * S_ + q0 + r) * NQKV_ + h * HD_;
    #pragma unroll
    for (int rep = 0; rep < 8; ++rep) {
      const int d = d0 + rep * 16;
      const float4 v4 = *(const float4*)(qrow + d);
      qT[d + 0][r] = v4.x * QSCALE;
      qT[d + 1][r] = v4.y * QSCALE;
      qT[d + 2][r] = v4.z * QSCALE;
      qT[d + 3][r] = v4.w * QSCALE;
    }
  }

  float o_acc[2][4][4];
  #pragma unroll
  for (int cb = 0; cb < 2; ++cb)
    #pragma unroll
    for (int i = 0; i < 4; ++i)
      #pragma unroll
      for (int cc = 0; cc < 4; ++cc) o_acc[cb][i][cc] = 0.f;
  float m_i[4], l_i[4];
  #pragma unroll
  for (int i = 0; i < 4; ++i) { m_i[i] = -1e30f; l_i[i] = 0.f; }

  const int jload  = t >> 2;
  const int dload0 = (t & 3) * 4;
  const int vj     = ((t & 63) >> 2) + 16 * (t >> 6);

  for (int kt = 0; kt <= qt; ++kt) {
    const int k0 = kt * 64;
    __syncthreads();
    {
      const float* krow = qkv + (size_t)(b * S_ + k0 + jload) * NQKV_ + 2048 + kvh * HD_;
      #pragma unroll
      for (int rep = 0; rep < 8; ++rep) {
        const int d = dload0 + rep * 16;
        const float4 v4 = *(const float4*)(krow + d);
        kv[(d + 0) * 64 + jload] = v4.x;
        kv[(d + 1) * 64 + jload] = v4.y;
        kv[(d + 2) * 64 + jload] = v4.z;
        kv[(d + 3) * 64 + jload] = v4.w;
      }
    }
    __syncthreads();

    float s_reg[4][4];
    #pragma unroll
    for (int i = 0; i < 4; ++i)
      #pragma unroll
      for (int jj = 0; jj < 4; ++jj) s_reg[i][jj] = 0.f;

    #pragma unroll 8
    for (int d = 0; d < 128; ++d) {
      const float4 a4 = *(const float4*)&qT[d][4 * ty];
      const float4 b4 = *(const float4*)&kv[d * 64 + 4 * tx];
      const float aq[4] = {a4.x, a4.y, a4.z, a4.w};
      const float bk[4] = {b4.x, b4.y, b4.z, b4.w};
      #pragma unroll
      for (int i = 0; i < 4; ++i)
        #pragma unroll
        for (int jj = 0; jj < 4; ++jj)
          s_reg[i][jj] = fmaf(aq[i], bk[jj], s_reg[i][jj]);
    }

    if (kt == qt) {
      #pragma unroll
      for (int i = 0; i < 4; ++i)
        #pragma unroll
        for (int jj = 0; jj < 4; ++jj)
          if (4 * tx + jj > 4 * ty + i) s_reg[i][jj] = -1e30f;
    }

    #pragma unroll
    for (int i = 0; i < 4; ++i) {
      float rm = fmaxf(fmaxf(s_reg[i][0], s_reg[i][1]),
                       fmaxf(s_reg[i][2], s_reg[i][3]));
      #pragma unroll
      for (int msk = 1; msk < 16; msk <<= 1) rm = fmaxf(rm, __shfl_xor(rm, msk, 64));
      const float mn    = fmaxf(m_i[i], rm);
      const float alpha = __expf(m_i[i] - mn);
      float ps = 0.f;
      #pragma unroll
      for (int jj = 0; jj < 4; ++jj) {
        const float p = __expf(s_reg[i][jj] - mn);
        s_reg[i][jj] = p;
        ps += p;
      }
      #pragma unroll
      for (int msk = 1; msk < 16; msk <<= 1) ps += __shfl_xor(ps, msk, 64);
      l_i[i] = l_i[i] * alpha + ps;
      m_i[i] = mn;
      #pragma unroll
      for (int cb = 0; cb < 2; ++cb)
        #pragma unroll
        for (int cc = 0; cc < 4; ++cc) o_acc[cb][i][cc] *= alpha;
    }

    #pragma unroll
    for (int i = 0; i < 4; ++i)
      *(float4*)&sP[4 * ty + i][4 * tx] =
          make_float4(s_reg[i][0], s_reg[i][1], s_reg[i][2], s_reg[i][3]);
    __syncthreads();

    {
      const float* vrow = qkv + (size_t)(b * S_ + k0 + vj) * NQKV_ + 2560 + kvh * HD_;
      #pragma unroll
      for (int rep = 0; rep < 8; ++rep) {
        const int d = dload0 + rep * 16;
        const float4 v4 = *(const float4*)(vrow + d);
        const int ch = (((d >> 2) + vj) & 31) << 2;
        *(float4*)&kv[vj * 128 + ch] = v4;
      }
    }
    __syncthreads();

    #pragma unroll 2
    for (int j0 = 0; j0 < 64; j0 += 4) {
      float pf[4][4];
      #pragma unroll
      for (int i = 0; i < 4; ++i)
        *(float4*)pf[i] = *(const float4*)&sP[4 * ty + i][j0];
      #pragma unroll
      for (int jj = 0; jj < 4; ++jj) {
        const int j = j0 + jj;
        const float4 v0 = *(const float4*)&kv[j * 128 + (((tx + j) & 31) << 2)];
        const float4 v1 = *(const float4*)&kv[j * 128 + (((tx + 16 + j) & 31) << 2)];
        const float vr[2][4] = {{v0.x, v0.y, v0.z, v0.w},
                                {v1.x, v1.y, v1.z, v1.w}};
        #pragma unroll
        for (int i = 0; i < 4; ++i) {
          const float p = pf[i][jj];
          #pragma unroll
          for (int cc = 0; cc < 4; ++cc) {
            o_acc[0][i][cc] = fmaf(p, vr[0][cc], o_acc[0][i][cc]);
            o_acc[1][i][cc] = fmaf(p, vr[1][cc], o_acc[1][i][cc]);
          }
        }
      }
    }
  }

  // normalize + split-write (hi/lo bf16) for the WO GEMM
  #pragma unroll
  for (int i = 0; i < 4; ++i) {
    const float inv = 1.0f / l_i[i];
    const size_t ro = (size_t)(b * S_ + q0 + 4 * ty + i) * 4096 + h * HD_;
    short h0[4], l0[4], h1[4], l1[4];
    #pragma unroll
    for (int cc = 0; cc < 4; ++cc) {
      split2(o_acc[0][i][cc] * inv, h0[cc], l0[cc]);
      split2(o_acc[1][i][cc] * inv, h1[cc], l1[cc]);
    }
    *(short4*)&osp[ro + 4 * tx]             = make_short4(h0[0], h0[1], h0[2], h0[3]);
    *(short4*)&osp[ro + 64 + 4 * tx]        = make_short4(h1[0], h1[1], h1[2], h1[3]);
    *(short4*)&osp[ro + 2048 + 4 * tx]      = make_short4(l0[0], l0[1], l0[2], l0[3]);
    *(short4*)&osp[ro + 2048 + 64 + 4 * tx] = make_short4(l1[0], l1[1], l1[2], l1[3]);
  }
}

// ---------------------------------------------------------------------------
extern "C" void kernel_launch(void* const* d_in, const int* in_sizes, int n_in,
                              void* d_out, int out_size, void* d_ws, size_t ws_size,
                              hipStream_t stream) {
  const float* hidden = (const float*)d_in[0];
  const float* wq     = (const float*)d_in[1];
  const float* wk     = (const float*)d_in[2];
  const float* wv     = (const float*)d_in[3];
  const float* wo     = (const float*)d_in[4];
  const float* qw     = (const float*)d_in[5];
  const float* kw     = (const float*)d_in[6];
  const int*   pos    = (const int*)d_in[7];
  float*       out    = (float*)d_out;

  // Workspace layout (bytes):
  //   R0 [0,   32MB): Asp = hidden split (M x 4096 bf16); reused as attn-out split
  //   R1 [32MB, 56MB): Bsp = weight splits (QKV fused N=3072, later WO N=2048)
  //   R2 [56MB, 104MB): qkv fp32 (M x 3072)
  const size_t aspB = (size_t)M_ * 4096 * 2;        // 33,554,432
  const size_t bspB = (size_t)NQKV_ * 4096 * 2;     // 25,165,824
  const size_t qkvB = (size_t)M_ * NQKV_ * 4;       // 50,331,648
  if (ws_size < aspB + bspB + qkvB) return;         // visible failure

  short* Asp = (short*)d_ws;
  short* Bsp = (short*)((char*)d_ws + aspB);
  float* qkv = (float*)((char*)d_ws + aspB + bspB);
  short* Osp = Asp;   // attn output split reuses R0 (hidden split dead by then)

  // 1) precision splits
  split_hidden<<<(M_ * D_ / 4) / 256, 256, 0, stream>>>((const float4*)hidden, Asp);
  tsplit<<<dim3(2048 / 32, 64), dim3(32, 8), 0, stream>>>(wq, 2048, Bsp, 0);
  tsplit<<<dim3(512 / 32, 64),  dim3(32, 8), 0, stream>>>(wk, 512,  Bsp, 2048);
  tsplit<<<dim3(512 / 32, 64),  dim3(32, 8), 0, stream>>>(wv, 512,  Bsp, 2560);

  // 2) fused QKV projection (split-bf16 MFMA)
  gemm_split_bf16<<<dim3(NQKV_ / 128, M_ / 128), 256, 0, stream>>>(
      Asp, Bsp, qkv, M_, NQKV_, 2048);

  // 3) RMSNorm + RoPE in place
  rmsrope<<<M_ * (H_ + HKV_), 64, 0, stream>>>(qkv, qw, kw, pos);

  // 4) causal GQA attention -> split bf16 output (into R0)
  attn<<<dim3(S_ / 64, B_ * H_), 256, 0, stream>>>(qkv, Osp);

  // 5) WO weight split (reuses R1 after QKV GEMM is done) + output projection
  tsplit<<<dim3(2048 / 32, 64), dim3(32, 8), 0, stream>>>(wo, 2048, Bsp, 0);
  gemm_split_bf16<<<dim3(D_ / 128, M_ / 128), 256, 0, stream>>>(
      Osp, Bsp, out, M_, D_, 2048);
}

// Round 3
// 674.238 us; speedup vs baseline: 3.8652x; 2.2813x over previous
//
#include <hip/hip_runtime.h>
#include <hip/hip_bf16.h>
#include <cstddef>

// Problem constants (Qwen3-style attention block, fp32 in/out)
constexpr int B_   = 2;
constexpr int S_   = 2048;
constexpr int D_   = 2048;
constexpr int H_   = 16;
constexpr int HKV_ = 4;
constexpr int HD_  = 128;
constexpr int M_   = B_ * S_;        // 4096 token rows
constexpr int NQKV_ = H_ * HD_ + 2 * HKV_ * HD_;  // 3072 fused QKV cols
constexpr float QSCALE = 0.08838834764831845f;    // 1/sqrt(128)

typedef __attribute__((ext_vector_type(8))) short bs8;   // 8 bf16 (4 VGPR)
typedef __attribute__((ext_vector_type(4))) float fx4;   // MFMA accumulator

// ---------------------------------------------------------------------------
// helpers
// ---------------------------------------------------------------------------
__device__ __forceinline__ void split2(float x, short& hi, short& lo) {
  __hip_bfloat16 h = __float2bfloat16(x);          // RNE
  float hf = __bfloat162float(h);
  __hip_bfloat16 l = __float2bfloat16(x - hf);
  hi = *(short*)&h;
  lo = *(short*)&l;
}

__device__ __forceinline__ void gload16(const short* g, short* l) {
  __builtin_amdgcn_global_load_lds(
      (const __attribute__((address_space(1))) void*)g,
      (__attribute__((address_space(3))) void*)l, 16, 0, 0);
}

// ---------------------------------------------------------------------------
// Split hidden (M x 2048 fp32) -> Asp (M x 4096 bf16, cols [0,2048)=hi, [2048,4096)=lo)
// ---------------------------------------------------------------------------
__global__ __launch_bounds__(256) void split_hidden(
    const float4* __restrict__ X, short* __restrict__ out)
{
  const long i4  = (long)blockIdx.x * 256 + threadIdx.x;  // M*2048/4 float4s
  const long row = i4 >> 9;                               // 512 float4 per row
  const long c   = (i4 & 511) * 4;
  const float4 v = X[i4];
  short h[4], l[4];
  split2(v.x, h[0], l[0]); split2(v.y, h[1], l[1]);
  split2(v.z, h[2], l[2]); split2(v.w, h[3], l[3]);
  *(short4*)&out[row * 4096 + c]        = make_short4(h[0], h[1], h[2], h[3]);
  *(short4*)&out[row * 4096 + 2048 + c] = make_short4(l[0], l[1], l[2], l[3]);
}

// ---------------------------------------------------------------------------
// Transpose+split a weight W (2048 x N fp32, row-major) into
// out[(row0+n)*4096 + k] = hi(W[k][n]), out[(row0+n)*4096 + 2048 + k] = lo.
// ---------------------------------------------------------------------------
__global__ __launch_bounds__(256) void tsplit(
    const float* __restrict__ W, int N, short* __restrict__ out, int row0)
{
  __shared__ float tile[32][33];
  const int k0 = blockIdx.y * 32;
  const int n0 = blockIdx.x * 32;
  const int x = threadIdx.x, y = threadIdx.y;
  #pragma unroll
  for (int i = 0; i < 4; ++i)
    tile[y + 8 * i][x] = W[(size_t)(k0 + y + 8 * i) * N + n0 + x];
  __syncthreads();
  #pragma unroll
  for (int i = 0; i < 4; ++i) {
    const int n = n0 + y + 8 * i;
    const float v = tile[x][y + 8 * i];
    short hi, lo;
    split2(v, hi, lo);
    out[(size_t)(row0 + n) * 4096 + k0 + x]        = hi;
    out[(size_t)(row0 + n) * 4096 + 2048 + k0 + x] = lo;
  }
}

// ---------------------------------------------------------------------------
// Split-bf16 MFMA GEMM (m97 structure) — unchanged from round 2 (validated).
// ---------------------------------------------------------------------------
__global__ __launch_bounds__(256, 2) void gemm_split_bf16(
    const short* __restrict__ Asp, const short* __restrict__ Bsp,
    float* __restrict__ C, int M, int N, int K)
{
  __shared__ short As[128 * 32];
  __shared__ short Bs[128 * 32];

  const int t    = threadIdx.x;
  const int lane = t & 63, wid = t >> 6;
  const int wr   = wid >> 1, wc = wid & 1;
  const int bm   = blockIdx.y * 128, bn = blockIdx.x * 128;
  const int ld   = 2 * K;

  fx4 acc[4][4] = {};

  const int sr = t >> 2;
  const int sk = (t & 3) * 8;
  short* lA  = As + t * 8;
  short* lA2 = As + (t + 256) * 8;
  short* lB  = Bs + t * 8;
  short* lB2 = Bs + (t + 256) * 8;
  const short* gA = Asp + (size_t)(bm + sr) * ld + sk;
  const short* gB = Bsp + (size_t)(bn + sr) * ld + sk;
  const size_t rstep = (size_t)64 * ld;

  const int lr = lane & 15, lk = (lane >> 4) * 8;

  for (int kp = 0; kp < 3 * K; kp += 32) {
    const int ca = (kp < 2 * K) ? kp : kp - 2 * K;  // A col base (hi|lo|hi)
    const int cb = (kp < K) ? kp : kp - K;          // B col base (hi|hi|lo)
    gload16(gA + ca, lA);
    gload16(gA + ca + rstep, lA2);
    gload16(gB + cb, lB);
    gload16(gB + cb + rstep, lB2);
    __syncthreads();

    bs8 af[4], bf[4];
    #pragma unroll
    for (int m = 0; m < 4; ++m)
      af[m] = *(const bs8*)&As[(wr * 64 + m * 16 + lr) * 32 + lk];
    #pragma unroll
    for (int n = 0; n < 4; ++n)
      bf[n] = *(const bs8*)&Bs[(wc * 64 + n * 16 + lr) * 32 + lk];
    #pragma unroll
    for (int m = 0; m < 4; ++m)
      #pragma unroll
      for (int n = 0; n < 4; ++n)
        acc[m][n] = __builtin_amdgcn_mfma_f32_16x16x32_bf16(af[m], bf[n], acc[m][n], 0, 0, 0);
    __syncthreads();
  }

  const int lg = lane >> 4;
  #pragma unroll
  for (int m = 0; m < 4; ++m)
    #pragma unroll
    for (int n = 0; n < 4; ++n) {
      const int col = bn + wc * 64 + n * 16 + lr;
      #pragma unroll
      for (int r = 0; r < 4; ++r) {
        const int row = bm + wr * 64 + m * 16 + lg * 4 + r;
        C[(size_t)row * N + col] = acc[m][n][r];
      }
    }
}

// ---------------------------------------------------------------------------
// Fused RMSNorm + RoPE. Q rows: in-place fp32. K rows: after norm+rope,
// write hi/lo bf16 IN PLACE over the fp32 row (srow[0..127]=hi, [128..255]=lo).
// Safe: one wave per row; all lane loads complete before any store (shuffle dep).
// ---------------------------------------------------------------------------
__global__ __launch_bounds__(64) void rmsrope(
    float* __restrict__ qkv, const float* __restrict__ qw,
    const float* __restrict__ kw, const int* __restrict__ pos_ids)
{
  const int row  = blockIdx.x;
  const int lane = threadIdx.x;
  constexpr int NQROWS = M_ * H_;
  const bool isq = row < NQROWS;

  int token; float* ptr; const float* w;
  if (isq) {
    token = row / H_;
    ptr = qkv + (size_t)token * NQKV_ + (row % H_) * HD_;
    w = qw;
  } else {
    const int rk = row - NQROWS;
    token = rk / HKV_;
    ptr = qkv + (size_t)token * NQKV_ + 2048 + (rk % HKV_) * HD_;
    w = kw;
  }

  const float x1 = ptr[lane];
  const float x2 = ptr[lane + 64];
  float ss = x1 * x1 + x2 * x2;
  #pragma unroll
  for (int m = 1; m < 64; m <<= 1) ss += __shfl_xor(ss, m, 64);
  const float rinv = rsqrtf(ss * (1.0f / 128.0f) + 1e-6f);
  const float y1 = x1 * rinv * w[lane];
  const float y2 = x2 * rinv * w[lane + 64];

  const int pos = pos_ids[token];
  const float f = (float)pos * powf(10000.0f, -(float)lane * (1.0f / 64.0f));
  float sn, c;
  sincosf(f, &sn, &c);
  const float o1 = y1 * c - y2 * sn;
  const float o2 = y2 * c + y1 * sn;

  if (isq) {
    ptr[lane]      = o1;
    ptr[lane + 64] = o2;
  } else {
    short* srow = (short*)ptr;
    short h1, l1, h2, l2;
    split2(o1, h1, l1);
    split2(o2, h2, l2);
    srow[lane]       = h1;  srow[lane + 64]  = h2;   // hi[0..127]
    srow[128 + lane] = l1;  srow[192 + lane] = l2;   // lo[0..127]
  }
}

// ---------------------------------------------------------------------------
// V transpose+cast: qkv V region (fp32 [token][2560 + kvh*128 + d]) ->
// Vsp[(b*HKV+kvh)*128 + d][s] bf16  (row-major over s, ld = S)
// ---------------------------------------------------------------------------
__global__ __launch_bounds__(256) void vtrans(
    const float* __restrict__ qkv, short* __restrict__ vsp)
{
  __shared__ float tile[32][33];
  const int by = blockIdx.y;
  const int b = by >> 4, kvh = (by >> 2) & 3, d0 = (by & 3) * 32;
  const int s0 = blockIdx.x * 32;
  const int tx = threadIdx.x, ty = threadIdx.y;
  #pragma unroll
  for (int i = 0; i < 4; ++i)
    tile[ty + 8 * i][tx] =
        qkv[(size_t)(b * S_ + s0 + ty + 8 * i) * NQKV_ + 2560 + kvh * 128 + d0 + tx];
  __syncthreads();
  #pragma unroll
  for (int i = 0; i < 4; ++i) {
    const int d = d0 + ty + 8 * i;
    __hip_bfloat16 v = __float2bfloat16(tile[tx][ty + 8 * i]);
    vsp[((size_t)(b * HKV_ + kvh) * 128 + d) * (size_t)S_ + s0 + tx] = *(short*)&v;
  }
}

// ---------------------------------------------------------------------------
// MFMA causal GQA flash attention.
// Block = (64-row Q tile, b, h), 4 waves; wave w owns S-rows 16w..16w+15.
// Q: registers (scaled, hi/lo split). K: LDS [64][128] bf16 hi+lo, XOR-swizzled.
// S = Qh*Kh + Ql*Kh + Qh*Kl (3-term, fp32-grade). Softmax: 16-lane shuffles.
// P: bf16 via per-wave-private swizzled LDS tile. V: from pre-transposed Vsp.
// LDS = 16+16+16+8 = 56KB -> 2 blocks/CU.
// ---------------------------------------------------------------------------
__global__ __launch_bounds__(256, 2) void attn_mfma(
    const float* __restrict__ qkv, const short* __restrict__ vsp,
    short* __restrict__ osp)
{
  __shared__ __align__(16) short Kh[64 * 128];
  __shared__ __align__(16) short Kl[64 * 128];
  __shared__ __align__(16) short Vt[128 * 64];   // [d][j]
  __shared__ __align__(16) short sP[64 * 64];    // [r][j]

  const int t    = threadIdx.x;
  const int lane = t & 63;
  const int w    = t >> 6;        // wave id -> S-row block
  const int lr   = lane & 15;     // frag row/col selector
  const int g    = lane >> 4;     // frag k-chunk selector
  const int qt = blockIdx.x, bh = blockIdx.y;
  const int b = bh >> 4, h = bh & 15;
  const int kvh = h >> 2;
  const int q0  = qt * 64;
  const int bhk = b * HKV_ + kvh;
  const short* kb = (const short*)qkv;   // K region overlaid bf16 by rmsrope

  // ---- Q fragments (rows 16w+lr), scaled + split ----
  bs8 qh[4], ql[4];
  {
    const float* qrow = qkv + (size_t)(b * S_ + q0 + 16 * w + lr) * NQKV_ + h * HD_ + g * 8;
    #pragma unroll
    for (int dc = 0; dc < 4; ++dc) {
      float x[8];
      *(float4*)&x[0] = *(const float4*)(qrow + 32 * dc);
      *(float4*)&x[4] = *(const float4*)(qrow + 32 * dc + 4);
      #pragma unroll
      for (int i = 0; i < 8; ++i) {
        short hi, lo;
        split2(x[i] * QSCALE, hi, lo);
        qh[dc][i] = hi; ql[dc][i] = lo;
      }
    }
  }

  fx4 o[8] = {};
  float m_i[4] = {-1e30f, -1e30f, -1e30f, -1e30f};
  float l_i[4] = {0.f, 0.f, 0.f, 0.f};

  const int sj = t >> 2, sq = t & 3;    // K staging: row, 32-col chunk
  const int vd = t >> 1, vjh = t & 1;   // V staging: d-row, 32-col half

  for (int kt = 0; kt <= qt; ++kt) {
    const int k0 = kt * 64;
    __syncthreads();   // previous tile's LDS reads complete

    // ---- stage K (hi/lo, swizzled) + V (transposed rows, swizzled) ----
    {
      const short* krow = kb + (size_t)(b * S_ + k0 + sj) * 6144 + 4096 + kvh * 256 + 32 * sq;
      const short* vrow = vsp + ((size_t)bhk * 128 + vd) * (size_t)S_ + k0 + 32 * vjh;
      #pragma unroll
      for (int ci = 0; ci < 4; ++ci) {
        const int kblk = (((4 * sq + ci) ^ (sj & 15)) << 3);
        *(bs8*)&Kh[sj * 128 + kblk] = *(const bs8*)(krow + 8 * ci);
        *(bs8*)&Kl[sj * 128 + kblk] = *(const bs8*)(krow + 128 + 8 * ci);
        *(bs8*)&Vt[vd * 64 + ((((4 * vjh + ci) ^ (vd & 7))) << 3)] = *(const bs8*)(vrow + 8 * ci);
      }
    }
    __syncthreads();

    // ---- S = Q K^T (3-term split, fp32 accum) ----
    fx4 s[4] = {};
    #pragma unroll
    for (int dc = 0; dc < 4; ++dc) {
      #pragma unroll
      for (int n = 0; n < 4; ++n) {
        const int ko = (16 * n + lr) * 128 + (((dc * 4 + g) ^ lr) << 3);
        const bs8 fh = *(const bs8*)&Kh[ko];
        const bs8 fl = *(const bs8*)&Kl[ko];
        s[n] = __builtin_amdgcn_mfma_f32_16x16x32_bf16(qh[dc], fh, s[n], 0, 0, 0);
        s[n] = __builtin_amdgcn_mfma_f32_16x16x32_bf16(ql[dc], fh, s[n], 0, 0, 0);
        s[n] = __builtin_amdgcn_mfma_f32_16x16x32_bf16(qh[dc], fl, s[n], 0, 0, 0);
      }
    }

    if (kt == qt) {   // causal mask on the diagonal tile
      #pragma unroll
      for (int n = 0; n < 4; ++n)
        #pragma unroll
        for (int r = 0; r < 4; ++r)
          if (16 * n + lr > 16 * w + 4 * g + r) s[n][r] = -1e30f;
    }

    // ---- online softmax (rows 16w + 4g + r) ----
    #pragma unroll
    for (int r = 0; r < 4; ++r) {
      float rm = fmaxf(fmaxf(s[0][r], s[1][r]), fmaxf(s[2][r], s[3][r]));
      rm = fmaxf(rm, __shfl_xor(rm, 1, 64));
      rm = fmaxf(rm, __shfl_xor(rm, 2, 64));
      rm = fmaxf(rm, __shfl_xor(rm, 4, 64));
      rm = fmaxf(rm, __shfl_xor(rm, 8, 64));
      const float mn    = fmaxf(m_i[r], rm);
      const float alpha = __expf(m_i[r] - mn);
      float ps = 0.f;
      #pragma unroll
      for (int n = 0; n < 4; ++n) {
        const float p = __expf(s[n][r] - mn);
        s[n][r] = p;
        ps += p;
      }
      ps += __shfl_xor(ps, 1, 64);
      ps += __shfl_xor(ps, 2, 64);
      ps += __shfl_xor(ps, 4, 64);
      ps += __shfl_xor(ps, 8, 64);
      l_i[r] = l_i[r] * alpha + ps;
      m_i[r] = mn;
      #pragma unroll
      for (int df = 0; df < 8; ++df) o[df][r] *= alpha;

      // P row -> bf16 -> per-wave-private swizzled LDS (no barrier needed)
      const int rr = 16 * w + 4 * g + r;
      #pragma unroll
      for (int n = 0; n < 4; ++n) {
        __hip_bfloat16 pb = __float2bfloat16(s[n][r]);
        sP[rr * 64 + ((((2 * n + (lr >> 3)) ^ (rr & 7))) << 3) + (lr & 7)] = *(short*)&pb;
      }
    }

    // ---- PV accumulate ----
    const int pro = (16 * w + lr) * 64;
    const bs8 pa0 = *(const bs8*)&sP[pro + (((g)     ^ (lr & 7)) << 3)];
    const bs8 pa1 = *(const bs8*)&sP[pro + (((g + 4) ^ (lr & 7)) << 3)];
    #pragma unroll
    for (int df = 0; df < 8; ++df) {
      const int vo = (16 * df + lr) * 64;
      const bs8 v0 = *(const bs8*)&Vt[vo + (((g)     ^ (lr & 7)) << 3)];
      const bs8 v1 = *(const bs8*)&Vt[vo + (((g + 4) ^ (lr & 7)) << 3)];
      o[df] = __builtin_amdgcn_mfma_f32_16x16x32_bf16(pa0, v0, o[df], 0, 0, 0);
      o[df] = __builtin_amdgcn_mfma_f32_16x16x32_bf16(pa1, v1, o[df], 0, 0, 0);
    }
  }

  // ---- normalize + hi/lo split write for WO GEMM ----
  #pragma unroll
  for (int r = 0; r < 4; ++r) {
    const float inv = 1.0f / l_i[r];
    const size_t ro = (size_t)(b * S_ + q0 + 16 * w + 4 * g + r) * 4096 + h * HD_;
    #pragma unroll
    for (int df = 0; df < 8; ++df) {
      short hi, lo;
      split2(o[df][r] * inv, hi, lo);
      osp[ro + 16 * df + lr]        = hi;
      osp[ro + 2048 + 16 * df + lr] = lo;
    }
  }
}

// ---------------------------------------------------------------------------
extern "C" void kernel_launch(void* const* d_in, const int* in_sizes, int n_in,
                              void* d_out, int out_size, void* d_ws, size_t ws_size,
                              hipStream_t stream) {
  const float* hidden = (const float*)d_in[0];
  const float* wq     = (const float*)d_in[1];
  const float* wk     = (const float*)d_in[2];
  const float* wv     = (const float*)d_in[3];
  const float* wo     = (const float*)d_in[4];
  const float* qw     = (const float*)d_in[5];
  const float* kw     = (const float*)d_in[6];
  const int*   pos    = (const int*)d_in[7];
  float*       out    = (float*)d_out;

  // Workspace (104 MB, same high-water mark as round 2):
  //   R0 [0,32MB): Asp hidden split; reused as Osp (attn-out split)
  //   R1 [32,56MB): Bsp weight splits; rows 2048..2559 reused as Vsp after QKV GEMM
  //   R2 [56,104MB): qkv fp32 (K region overlaid bf16 hi/lo by rmsrope)
  const size_t aspB = (size_t)M_ * 4096 * 2;
  const size_t bspB = (size_t)NQKV_ * 4096 * 2;
  const size_t qkvB = (size_t)M_ * NQKV_ * 4;
  if (ws_size < aspB + bspB + qkvB) return;   // visible failure

  short* Asp = (short*)d_ws;
  short* Bsp = (short*)((char*)d_ws + aspB);
  float* qkv = (float*)((char*)d_ws + aspB + bspB);
  short* Osp = Asp;
  short* Vsp = Bsp + (size_t)2048 * 4096;   // 4MB inside dead QKV-weight rows

  // 1) precision splits
  split_hidden<<<(M_ * D_ / 4) / 256, 256, 0, stream>>>((const float4*)hidden, Asp);
  tsplit<<<dim3(2048 / 32, 64), dim3(32, 8), 0, stream>>>(wq, 2048, Bsp, 0);
  tsplit<<<dim3(512 / 32, 64),  dim3(32, 8), 0, stream>>>(wk, 512,  Bsp, 2048);
  tsplit<<<dim3(512 / 32, 64),  dim3(32, 8), 0, stream>>>(wv, 512,  Bsp, 2560);

  // 2) fused QKV projection
  gemm_split_bf16<<<dim3(NQKV_ / 128, M_ / 128), 256, 0, stream>>>(
      Asp, Bsp, qkv, M_, NQKV_, 2048);

  // 3) RMSNorm + RoPE (Q fp32 in place; K -> bf16 hi/lo in place)
  rmsrope<<<M_ * (H_ + HKV_), 64, 0, stream>>>(qkv, qw, kw, pos);

  // 4) V transpose+cast into Vsp
  vtrans<<<dim3(S_ / 32, 32), dim3(32, 8), 0, stream>>>(qkv, Vsp);

  // 5) MFMA flash attention -> Osp (hi/lo split, ld 4096)
  attn_mfma<<<dim3(S_ / 64, B_ * H_), 256, 0, stream>>>(qkv, Vsp, Osp);

  // 6) output projection
  tsplit<<<dim3(2048 / 32, 64), dim3(32, 8), 0, stream>>>(wo, 2048, Bsp, 0);
  gemm_split_bf16<<<dim3(D_ / 128, M_ / 128), 256, 0, stream>>>(
      Osp, Bsp, out, M_, D_, 2048);
}

// Round 4
// 633.065 us; speedup vs baseline: 4.1166x; 1.0650x over previous
//
#include <hip/hip_runtime.h>
#include <hip/hip_bf16.h>
#include <cstddef>

// Problem constants (Qwen3-style attention block, fp32 in/out)
constexpr int B_   = 2;
constexpr int S_   = 2048;
constexpr int D_   = 2048;
constexpr int H_   = 16;
constexpr int HKV_ = 4;
constexpr int HD_  = 128;
constexpr int M_   = B_ * S_;        // 4096 token rows
constexpr int NQKV_ = H_ * HD_ + 2 * HKV_ * HD_;  // 3072 fused QKV cols
constexpr float QSCALE = 0.08838834764831845f;    // 1/sqrt(128)

typedef __attribute__((ext_vector_type(8))) short bs8;   // 8 bf16 (4 VGPR)
typedef __attribute__((ext_vector_type(4))) float fx4;   // MFMA accumulator

// ---------------------------------------------------------------------------
// helpers
// ---------------------------------------------------------------------------
__device__ __forceinline__ void split2(float x, short& hi, short& lo) {
  __hip_bfloat16 h = __float2bfloat16(x);          // RNE
  float hf = __bfloat162float(h);
  __hip_bfloat16 l = __float2bfloat16(x - hf);
  hi = *(short*)&h;
  lo = *(short*)&l;
}

__device__ __forceinline__ void gload16(const short* g, short* l) {
  __builtin_amdgcn_global_load_lds(
      (const __attribute__((address_space(1))) void*)g,
      (__attribute__((address_space(3))) void*)l, 16, 0, 0);
}

__device__ __forceinline__ void bar_raw() {
  asm volatile("s_barrier" ::: "memory");
}
__device__ __forceinline__ void vmwait12() {
  asm volatile("s_waitcnt vmcnt(12)" ::: "memory");
}
__device__ __forceinline__ void vmwait0() {
  asm volatile("s_waitcnt vmcnt(0)" ::: "memory");
}

// ---------------------------------------------------------------------------
// Split hidden (M x 2048 fp32) -> Asp (M x 4096 bf16, cols [0,2048)=hi, lo after)
// ---------------------------------------------------------------------------
__global__ __launch_bounds__(256) void split_hidden(
    const float4* __restrict__ X, short* __restrict__ out)
{
  const long i4  = (long)blockIdx.x * 256 + threadIdx.x;
  const long row = i4 >> 9;
  const long c   = (i4 & 511) * 4;
  const float4 v = X[i4];
  short h[4], l[4];
  split2(v.x, h[0], l[0]); split2(v.y, h[1], l[1]);
  split2(v.z, h[2], l[2]); split2(v.w, h[3], l[3]);
  *(short4*)&out[row * 4096 + c]        = make_short4(h[0], h[1], h[2], h[3]);
  *(short4*)&out[row * 4096 + 2048 + c] = make_short4(l[0], l[1], l[2], l[3]);
}

// ---------------------------------------------------------------------------
// Transpose+split weight W (2048 x N fp32) -> out[(row0+n)*4096 + {k | 2048+k}]
// ---------------------------------------------------------------------------
__global__ __launch_bounds__(256) void tsplit(
    const float* __restrict__ W, int N, short* __restrict__ out, int row0)
{
  __shared__ float tile[32][33];
  const int k0 = blockIdx.y * 32;
  const int n0 = blockIdx.x * 32;
  const int x = threadIdx.x, y = threadIdx.y;
  #pragma unroll
  for (int i = 0; i < 4; ++i)
    tile[y + 8 * i][x] = W[(size_t)(k0 + y + 8 * i) * N + n0 + x];
  __syncthreads();
  #pragma unroll
  for (int i = 0; i < 4; ++i) {
    const int n = n0 + y + 8 * i;
    const float v = tile[x][y + 8 * i];
    short hi, lo;
    split2(v, hi, lo);
    out[(size_t)(row0 + n) * 4096 + k0 + x]        = hi;
    out[(size_t)(row0 + n) * 4096 + 2048 + k0 + x] = lo;
  }
}

// ---------------------------------------------------------------------------
// Split-bf16 MFMA GEMM (m97 structure), + XCD chunk swizzle (nwg % 8 == 0).
// ---------------------------------------------------------------------------
__global__ __launch_bounds__(256, 2) void gemm_split_bf16(
    const short* __restrict__ Asp, const short* __restrict__ Bsp,
    float* __restrict__ C, int M, int N, int K)
{
  __shared__ short As[128 * 32];
  __shared__ short Bs[128 * 32];

  const int t    = threadIdx.x;
  const int lane = t & 63, wid = t >> 6;
  const int wr   = wid >> 1, wc = wid & 1;

  // XCD-aware chunk swizzle: dispatch round-robins XCDs; give each XCD a
  // contiguous tile chunk (bijective since nwg % 8 == 0 for all our grids).
  const int nbx = gridDim.x;
  const int nwg = nbx * gridDim.y;
  int bid = blockIdx.y * nbx + blockIdx.x;
  bid = (bid & 7) * (nwg >> 3) + (bid >> 3);
  const int bm = (bid / nbx) * 128, bn = (bid % nbx) * 128;
  const int ld = 2 * K;

  fx4 acc[4][4] = {};

  const int sr = t >> 2;
  const int sk = (t & 3) * 8;
  short* lA  = As + t * 8;
  short* lA2 = As + (t + 256) * 8;
  short* lB  = Bs + t * 8;
  short* lB2 = Bs + (t + 256) * 8;
  const short* gA = Asp + (size_t)(bm + sr) * ld + sk;
  const short* gB = Bsp + (size_t)(bn + sr) * ld + sk;
  const size_t rstep = (size_t)64 * ld;

  const int lr = lane & 15, lk = (lane >> 4) * 8;

  for (int kp = 0; kp < 3 * K; kp += 32) {
    const int ca = (kp < 2 * K) ? kp : kp - 2 * K;  // A col base (hi|lo|hi)
    const int cb = (kp < K) ? kp : kp - K;          // B col base (hi|hi|lo)
    gload16(gA + ca, lA);
    gload16(gA + ca + rstep, lA2);
    gload16(gB + cb, lB);
    gload16(gB + cb + rstep, lB2);
    __syncthreads();

    bs8 af[4], bf[4];
    #pragma unroll
    for (int m = 0; m < 4; ++m)
      af[m] = *(const bs8*)&As[(wr * 64 + m * 16 + lr) * 32 + lk];
    #pragma unroll
    for (int n = 0; n < 4; ++n)
      bf[n] = *(const bs8*)&Bs[(wc * 64 + n * 16 + lr) * 32 + lk];
    #pragma unroll
    for (int m = 0; m < 4; ++m)
      #pragma unroll
      for (int n = 0; n < 4; ++n)
        acc[m][n] = __builtin_amdgcn_mfma_f32_16x16x32_bf16(af[m], bf[n], acc[m][n], 0, 0, 0);
    __syncthreads();
  }

  const int lg = lane >> 4;
  #pragma unroll
  for (int m = 0; m < 4; ++m)
    #pragma unroll
    for (int n = 0; n < 4; ++n) {
      const int col = bn + wc * 64 + n * 16 + lr;
      #pragma unroll
      for (int r = 0; r < 4; ++r) {
        const int row = bm + wr * 64 + m * 16 + lg * 4 + r;
        C[(size_t)row * N + col] = acc[m][n][r];
      }
    }
}

// ---------------------------------------------------------------------------
// Fused RMSNorm + RoPE. Q rows: in-place fp32. K rows: hi/lo bf16 overlay.
// ---------------------------------------------------------------------------
__global__ __launch_bounds__(64) void rmsrope(
    float* __restrict__ qkv, const float* __restrict__ qw,
    const float* __restrict__ kw, const int* __restrict__ pos_ids)
{
  const int row  = blockIdx.x;
  const int lane = threadIdx.x;
  constexpr int NQROWS = M_ * H_;
  const bool isq = row < NQROWS;

  int token; float* ptr; const float* w;
  if (isq) {
    token = row / H_;
    ptr = qkv + (size_t)token * NQKV_ + (row % H_) * HD_;
    w = qw;
  } else {
    const int rk = row - NQROWS;
    token = rk / HKV_;
    ptr = qkv + (size_t)token * NQKV_ + 2048 + (rk % HKV_) * HD_;
    w = kw;
  }

  const float x1 = ptr[lane];
  const float x2 = ptr[lane + 64];
  float ss = x1 * x1 + x2 * x2;
  #pragma unroll
  for (int m = 1; m < 64; m <<= 1) ss += __shfl_xor(ss, m, 64);
  const float rinv = rsqrtf(ss * (1.0f / 128.0f) + 1e-6f);
  const float y1 = x1 * rinv * w[lane];
  const float y2 = x2 * rinv * w[lane + 64];

  const int pos = pos_ids[token];
  const float f = (float)pos * powf(10000.0f, -(float)lane * (1.0f / 64.0f));
  float sn, c;
  sincosf(f, &sn, &c);
  const float o1 = y1 * c - y2 * sn;
  const float o2 = y2 * c + y1 * sn;

  if (isq) {
    ptr[lane]      = o1;
    ptr[lane + 64] = o2;
  } else {
    short* srow = (short*)ptr;
    short h1, l1, h2, l2;
    split2(o1, h1, l1);
    split2(o2, h2, l2);
    srow[lane]       = h1;  srow[lane + 64]  = h2;   // hi[0..127]
    srow[128 + lane] = l1;  srow[192 + lane] = l2;   // lo[0..127]
  }
}

// ---------------------------------------------------------------------------
// V transpose+cast: qkv V region -> Vsp[(b*HKV+kvh)*128 + d][s] bf16 (ld = S)
// ---------------------------------------------------------------------------
__global__ __launch_bounds__(256) void vtrans(
    const float* __restrict__ qkv, short* __restrict__ vsp)
{
  __shared__ float tile[32][33];
  const int by = blockIdx.y;
  const int b = by >> 4, kvh = (by >> 2) & 3, d0 = (by & 3) * 32;
  const int s0 = blockIdx.x * 32;
  const int tx = threadIdx.x, ty = threadIdx.y;
  #pragma unroll
  for (int i = 0; i < 4; ++i)
    tile[ty + 8 * i][tx] =
        qkv[(size_t)(b * S_ + s0 + ty + 8 * i) * NQKV_ + 2560 + kvh * 128 + d0 + tx];
  __syncthreads();
  #pragma unroll
  for (int i = 0; i < 4; ++i) {
    const int d = d0 + ty + 8 * i;
    __hip_bfloat16 v = __float2bfloat16(tile[tx][ty + 8 * i]);
    vsp[((size_t)(b * HKV_ + kvh) * 128 + d) * (size_t)S_ + s0 + tx] = *(short*)&v;
  }
}

// ---------------------------------------------------------------------------
// MFMA causal GQA flash attention v2.
// Block = 4 waves (256 thr), TWO fold-paired 128-row Q tiles {p, 15-p}
//   -> 34 K-tile iterations per block, grid 8x32 = 256 blocks = 1/CU, balanced.
// Wave owns 32 Q-rows (2 row-frags) -> K/V frags reused across m (half LDS reads).
// K/V staged by global_load_lds (pre-swizzled global addrs, linear LDS dest),
// double-buffered, prefetched 1 tile ahead with counted vmcnt(12) + raw barrier.
// LDS = 2*(16+16+16) + 16 = 112KB -> 1 block/CU.
// ---------------------------------------------------------------------------
__global__ __launch_bounds__(256, 1) void attn_mfma2(
    const float* __restrict__ qkv, const short* __restrict__ vsp,
    short* __restrict__ osp)
{
  __shared__ __align__(16) short KhB[2][64 * 128];
  __shared__ __align__(16) short KlB[2][64 * 128];
  __shared__ __align__(16) short VtB[2][128 * 64];
  __shared__ __align__(16) short sP[128 * 64];

  const int t    = threadIdx.x;
  const int lane = t & 63;
  const int w    = t >> 6;        // wave id: rows 32w..32w+31
  const int lr   = lane & 15;
  const int g    = lane >> 4;
  const int p  = blockIdx.x;      // fold pair index 0..7
  const int bh = blockIdx.y;
  const int b = bh >> 4, h = bh & 15;
  const int kvh = h >> 2;
  const int bhk = b * HKV_ + kvh;
  const short* kb = (const short*)qkv;   // K region overlaid bf16 by rmsrope

  // per-thread staging geometry (pre-swizzled global source, linear LDS dest)
  const int kidx[4] = {w * 256 + 0 * 64 + lane, w * 256 + 1 * 64 + lane,
                       w * 256 + 2 * 64 + lane, w * 256 + 3 * 64 + lane};

  const int qts[2] = {p, 15 - p};

  #pragma unroll 1
  for (int sg = 0; sg < 2; ++sg) {
    const int qt  = qts[sg];
    const int q0  = 128 * qt;
    const int ntk = 2 * qt + 2;

    // ---- Q fragments: rows 32w+16m+lr, k-chunks g*8 + 32*dc ----
    bs8 qh[2][4], ql[2][4];
    #pragma unroll
    for (int m = 0; m < 2; ++m) {
      const float* qrow =
          qkv + (size_t)(b * S_ + q0 + 32 * w + 16 * m + lr) * NQKV_ + h * HD_ + g * 8;
      #pragma unroll
      for (int dc = 0; dc < 4; ++dc) {
        float x[8];
        *(float4*)&x[0] = *(const float4*)(qrow + 32 * dc);
        *(float4*)&x[4] = *(const float4*)(qrow + 32 * dc + 4);
        #pragma unroll
        for (int e = 0; e < 8; ++e) {
          short hi, lo;
          split2(x[e] * QSCALE, hi, lo);
          qh[m][dc][e] = hi; ql[m][dc][e] = lo;
        }
      }
    }

    fx4 o[2][8] = {};
    float m_i[2][4], l_i[2][4];
    #pragma unroll
    for (int m = 0; m < 2; ++m)
      #pragma unroll
      for (int r = 0; r < 4; ++r) { m_i[m][r] = -1e30f; l_i[m][r] = 0.f; }

    // ---- stage tile 0 into buf 0, drain everything (incl. Q / prior stores) ----
    {
      const int k0 = 0;
      #pragma unroll
      for (int i = 0; i < 4; ++i) {
        const int idx = kidx[i];
        const int sj = idx >> 4, cc = idx & 15;
        const short* kr = kb + (size_t)(b * S_ + k0 + sj) * 6144 + 4096 + kvh * 256;
        gload16(kr + 8 * (cc ^ (sj & 15)), &KhB[0][(w * 4 + i) * 512]);
        gload16(kr + 128 + 8 * (cc ^ (sj & 15)), &KlB[0][(w * 4 + i) * 512]);
        const int d = idx >> 3, c2 = idx & 7;
        const short* vr = vsp + ((size_t)bhk * 128 + d) * (size_t)S_ + k0;
        gload16(vr + 8 * (c2 ^ (d & 7)), &VtB[0][(w * 4 + i) * 512]);
      }
    }
    vmwait0();
    bar_raw();

    int buf = 0;
    #pragma unroll 1
    for (int kt = 0; kt < ntk; ++kt) {
      const int k0 = 64 * kt;

      // ---- prefetch next tile into buf^1 (12 loads stay in flight) ----
      if (kt + 1 < ntk) {
        const int kn = 64 * (kt + 1);
        #pragma unroll
        for (int i = 0; i < 4; ++i) {
          const int idx = kidx[i];
          const int sj = idx >> 4, cc = idx & 15;
          const short* kr = kb + (size_t)(b * S_ + kn + sj) * 6144 + 4096 + kvh * 256;
          gload16(kr + 8 * (cc ^ (sj & 15)), &KhB[buf ^ 1][(w * 4 + i) * 512]);
          gload16(kr + 128 + 8 * (cc ^ (sj & 15)), &KlB[buf ^ 1][(w * 4 + i) * 512]);
          const int d = idx >> 3, c2 = idx & 7;
          const short* vr = vsp + ((size_t)bhk * 128 + d) * (size_t)S_ + kn;
          gload16(vr + 8 * (c2 ^ (d & 7)), &VtB[buf ^ 1][(w * 4 + i) * 512]);
        }
        vmwait12();   // current tile's 12 complete; next tile's 12 in flight
      } else {
        vmwait0();
      }
      bar_raw();      // all waves' current-tile data landed

      const short* Kh = KhB[buf];
      const short* Kl = KlB[buf];
      const short* Vt = VtB[buf];

      // ---- S = Q K^T (3-term split), B-frags reused across m ----
      fx4 s[2][4] = {};
      #pragma unroll
      for (int dc = 0; dc < 4; ++dc) {
        #pragma unroll
        for (int n = 0; n < 4; ++n) {
          const int ko = (16 * n + lr) * 128 + (((dc * 4 + g) ^ lr) << 3);
          const bs8 fh = *(const bs8*)&Kh[ko];
          const bs8 fl = *(const bs8*)&Kl[ko];
          #pragma unroll
          for (int m = 0; m < 2; ++m) {
            s[m][n] = __builtin_amdgcn_mfma_f32_16x16x32_bf16(qh[m][dc], fh, s[m][n], 0, 0, 0);
            s[m][n] = __builtin_amdgcn_mfma_f32_16x16x32_bf16(ql[m][dc], fh, s[m][n], 0, 0, 0);
            s[m][n] = __builtin_amdgcn_mfma_f32_16x16x32_bf16(qh[m][dc], fl, s[m][n], 0, 0, 0);
          }
        }
      }

      if (k0 + 64 > q0) {   // diagonal tiles: causal mask
        #pragma unroll
        for (int m = 0; m < 2; ++m)
          #pragma unroll
          for (int n = 0; n < 4; ++n)
            #pragma unroll
            for (int r = 0; r < 4; ++r)
              if (k0 + 16 * n + lr > q0 + 32 * w + 16 * m + 4 * g + r)
                s[m][n][r] = -1e30f;
      }

      // ---- online softmax (rows 32w+16m+4g+r) + P -> sP (wave-private) ----
      #pragma unroll
      for (int m = 0; m < 2; ++m) {
        #pragma unroll
        for (int r = 0; r < 4; ++r) {
          float rm = fmaxf(fmaxf(s[m][0][r], s[m][1][r]),
                           fmaxf(s[m][2][r], s[m][3][r]));
          rm = fmaxf(rm, __shfl_xor(rm, 1, 64));
          rm = fmaxf(rm, __shfl_xor(rm, 2, 64));
          rm = fmaxf(rm, __shfl_xor(rm, 4, 64));
          rm = fmaxf(rm, __shfl_xor(rm, 8, 64));
          const float mn    = fmaxf(m_i[m][r], rm);
          const float alpha = __expf(m_i[m][r] - mn);
          float ps = 0.f;
          #pragma unroll
          for (int n = 0; n < 4; ++n) {
            const float pv = __expf(s[m][n][r] - mn);
            s[m][n][r] = pv;
            ps += pv;
          }
          ps += __shfl_xor(ps, 1, 64);
          ps += __shfl_xor(ps, 2, 64);
          ps += __shfl_xor(ps, 4, 64);
          ps += __shfl_xor(ps, 8, 64);
          l_i[m][r] = l_i[m][r] * alpha + ps;
          m_i[m][r] = mn;
          #pragma unroll
          for (int df = 0; df < 8; ++df) o[m][df][r] *= alpha;

          const int rr = 32 * w + 16 * m + 4 * g + r;
          #pragma unroll
          for (int n = 0; n < 4; ++n) {
            __hip_bfloat16 pb = __float2bfloat16(s[m][n][r]);
            sP[rr * 64 + ((((2 * n + (lr >> 3)) ^ (rr & 7))) << 3) + (lr & 7)] = *(short*)&pb;
          }
        }
      }

      // ---- PV accumulate (V frags reused across m) ----
      bs8 pa[2][2];
      #pragma unroll
      for (int m = 0; m < 2; ++m) {
        const int pro = (32 * w + 16 * m + lr) * 64;
        pa[m][0] = *(const bs8*)&sP[pro + (((g)     ^ (lr & 7)) << 3)];
        pa[m][1] = *(const bs8*)&sP[pro + (((g + 4) ^ (lr & 7)) << 3)];
      }
      #pragma unroll
      for (int df = 0; df < 8; ++df) {
        const int vo = (16 * df + lr) * 64;
        const bs8 v0 = *(const bs8*)&Vt[vo + (((g)     ^ (lr & 7)) << 3)];
        const bs8 v1 = *(const bs8*)&Vt[vo + (((g + 4) ^ (lr & 7)) << 3)];
        #pragma unroll
        for (int m = 0; m < 2; ++m) {
          o[m][df] = __builtin_amdgcn_mfma_f32_16x16x32_bf16(pa[m][0], v0, o[m][df], 0, 0, 0);
          o[m][df] = __builtin_amdgcn_mfma_f32_16x16x32_bf16(pa[m][1], v1, o[m][df], 0, 0, 0);
        }
      }

      bar_raw();      // all reads of buf done before next prefetch overwrites buf^1
      buf ^= 1;
    }

    // ---- normalize + hi/lo split write for WO GEMM ----
    #pragma unroll
    for (int m = 0; m < 2; ++m)
      #pragma unroll
      for (int r = 0; r < 4; ++r) {
        const float inv = 1.0f / l_i[m][r];
        const size_t ro =
            (size_t)(b * S_ + q0 + 32 * w + 16 * m + 4 * g + r) * 4096 + h * HD_;
        #pragma unroll
        for (int df = 0; df < 8; ++df) {
          short hi, lo;
          split2(o[m][df][r] * inv, hi, lo);
          osp[ro + 16 * df + lr]        = hi;
          osp[ro + 2048 + 16 * df + lr] = lo;
        }
      }
  }
}

// ---------------------------------------------------------------------------
extern "C" void kernel_launch(void* const* d_in, const int* in_sizes, int n_in,
                              void* d_out, int out_size, void* d_ws, size_t ws_size,
                              hipStream_t stream) {
  const float* hidden = (const float*)d_in[0];
  const float* wq     = (const float*)d_in[1];
  const float* wk     = (const float*)d_in[2];
  const float* wv     = (const float*)d_in[3];
  const float* wo     = (const float*)d_in[4];
  const float* qw     = (const float*)d_in[5];
  const float* kw     = (const float*)d_in[6];
  const int*   pos    = (const int*)d_in[7];
  float*       out    = (float*)d_out;

  // Workspace (104 MB):
  //   R0 [0,32MB): Asp hidden split; reused as Osp (attn-out split)
  //   R1 [32,56MB): Bsp weight splits; rows 2048.. reused as Vsp after QKV GEMM
  //   R2 [56,104MB): qkv fp32 (K region overlaid bf16 hi/lo by rmsrope)
  const size_t aspB = (size_t)M_ * 4096 * 2;
  const size_t bspB = (size_t)NQKV_ * 4096 * 2;
  const size_t qkvB = (size_t)M_ * NQKV_ * 4;
  if (ws_size < aspB + bspB + qkvB) return;   // visible failure

  short* Asp = (short*)d_ws;
  short* Bsp = (short*)((char*)d_ws + aspB);
  float* qkv = (float*)((char*)d_ws + aspB + bspB);
  short* Osp = Asp;
  short* Vsp = Bsp + (size_t)2048 * 4096;   // 4MB inside dead QKV-weight rows

  // 1) precision splits
  split_hidden<<<(M_ * D_ / 4) / 256, 256, 0, stream>>>((const float4*)hidden, Asp);
  tsplit<<<dim3(2048 / 32, 64), dim3(32, 8), 0, stream>>>(wq, 2048, Bsp, 0);
  tsplit<<<dim3(512 / 32, 64),  dim3(32, 8), 0, stream>>>(wk, 512,  Bsp, 2048);
  tsplit<<<dim3(512 / 32, 64),  dim3(32, 8), 0, stream>>>(wv, 512,  Bsp, 2560);

  // 2) fused QKV projection
  gemm_split_bf16<<<dim3(NQKV_ / 128, M_ / 128), 256, 0, stream>>>(
      Asp, Bsp, qkv, M_, NQKV_, 2048);

  // 3) RMSNorm + RoPE (Q fp32 in place; K -> bf16 hi/lo in place)
  rmsrope<<<M_ * (H_ + HKV_), 64, 0, stream>>>(qkv, qw, kw, pos);

  // 4) V transpose+cast into Vsp
  vtrans<<<dim3(S_ / 32, 32), dim3(32, 8), 0, stream>>>(qkv, Vsp);

  // 5) MFMA flash attention v2 -> Osp (hi/lo split, ld 4096)
  attn_mfma2<<<dim3(8, B_ * H_), 256, 0, stream>>>(qkv, Vsp, Osp);

  // 6) output projection
  tsplit<<<dim3(2048 / 32, 64), dim3(32, 8), 0, stream>>>(wo, 2048, Bsp, 0);
  gemm_split_bf16<<<dim3(D_ / 128, M_ / 128), 256, 0, stream>>>(
      Osp, Bsp, out, M_, D_, 2048);
}

// Round 5
// 594.472 us; speedup vs baseline: 4.3839x; 1.0649x over previous
//
#include <hip/hip_runtime.h>
#include <hip/hip_bf16.h>
#include <cstddef>

// Problem constants (Qwen3-style attention block, fp32 in/out)
constexpr int B_   = 2;
constexpr int S_   = 2048;
constexpr int D_   = 2048;
constexpr int H_   = 16;
constexpr int HKV_ = 4;
constexpr int HD_  = 128;
constexpr int M_   = B_ * S_;        // 4096 token rows
constexpr int NQKV_ = H_ * HD_ + 2 * HKV_ * HD_;  // 3072 fused QKV cols
constexpr float QSCALE = 0.08838834764831845f;    // 1/sqrt(128)

typedef __attribute__((ext_vector_type(8))) short bs8;   // 8 bf16 (4 VGPR)
typedef __attribute__((ext_vector_type(4))) float fx4;   // MFMA accumulator

// ---------------------------------------------------------------------------
// helpers
// ---------------------------------------------------------------------------
__device__ __forceinline__ void split2(float x, short& hi, short& lo) {
  __hip_bfloat16 h = __float2bfloat16(x);          // RNE
  float hf = __bfloat162float(h);
  __hip_bfloat16 l = __float2bfloat16(x - hf);
  hi = *(short*)&h;
  lo = *(short*)&l;
}

__device__ __forceinline__ void gload16(const short* g, short* l) {
  __builtin_amdgcn_global_load_lds(
      (const __attribute__((address_space(1))) void*)g,
      (__attribute__((address_space(3))) void*)l, 16, 0, 0);
}

// ---------------------------------------------------------------------------
// Split hidden (M x 2048 fp32) -> Asp (M x 4096 bf16, cols [0,2048)=hi, lo after)
// ---------------------------------------------------------------------------
__global__ __launch_bounds__(256) void split_hidden(
    const float4* __restrict__ X, short* __restrict__ out)
{
  const long i4  = (long)blockIdx.x * 256 + threadIdx.x;
  const long row = i4 >> 9;
  const long c   = (i4 & 511) * 4;
  const float4 v = X[i4];
  short h[4], l[4];
  split2(v.x, h[0], l[0]); split2(v.y, h[1], l[1]);
  split2(v.z, h[2], l[2]); split2(v.w, h[3], l[3]);
  *(short4*)&out[row * 4096 + c]        = make_short4(h[0], h[1], h[2], h[3]);
  *(short4*)&out[row * 4096 + 2048 + c] = make_short4(l[0], l[1], l[2], l[3]);
}

// ---------------------------------------------------------------------------
// Transpose+split weight W (2048 x N fp32) -> out[(row0+n)*4096 + {k | 2048+k}]
// ---------------------------------------------------------------------------
__global__ __launch_bounds__(256) void tsplit(
    const float* __restrict__ W, int N, short* __restrict__ out, int row0)
{
  __shared__ float tile[32][33];
  const int k0 = blockIdx.y * 32;
  const int n0 = blockIdx.x * 32;
  const int x = threadIdx.x, y = threadIdx.y;
  #pragma unroll
  for (int i = 0; i < 4; ++i)
    tile[y + 8 * i][x] = W[(size_t)(k0 + y + 8 * i) * N + n0 + x];
  __syncthreads();
  #pragma unroll
  for (int i = 0; i < 4; ++i) {
    const int n = n0 + y + 8 * i;
    const float v = tile[x][y + 8 * i];
    short hi, lo;
    split2(v, hi, lo);
    out[(size_t)(row0 + n) * 4096 + k0 + x]        = hi;
    out[(size_t)(row0 + n) * 4096 + 2048 + k0 + x] = lo;
  }
}

// ---------------------------------------------------------------------------
// Split-bf16 MFMA GEMM (m97 structure), + XCD chunk swizzle (nwg % 8 == 0).
// ---------------------------------------------------------------------------
__global__ __launch_bounds__(256, 2) void gemm_split_bf16(
    const short* __restrict__ Asp, const short* __restrict__ Bsp,
    float* __restrict__ C, int M, int N, int K)
{
  __shared__ short As[128 * 32];
  __shared__ short Bs[128 * 32];

  const int t    = threadIdx.x;
  const int lane = t & 63, wid = t >> 6;
  const int wr   = wid >> 1, wc = wid & 1;

  const int nbx = gridDim.x;
  const int nwg = nbx * gridDim.y;
  int bid = blockIdx.y * nbx + blockIdx.x;
  bid = (bid & 7) * (nwg >> 3) + (bid >> 3);
  const int bm = (bid / nbx) * 128, bn = (bid % nbx) * 128;
  const int ld = 2 * K;

  fx4 acc[4][4] = {};

  const int sr = t >> 2;
  const int sk = (t & 3) * 8;
  short* lA  = As + t * 8;
  short* lA2 = As + (t + 256) * 8;
  short* lB  = Bs + t * 8;
  short* lB2 = Bs + (t + 256) * 8;
  const short* gA = Asp + (size_t)(bm + sr) * ld + sk;
  const short* gB = Bsp + (size_t)(bn + sr) * ld + sk;
  const size_t rstep = (size_t)64 * ld;

  const int lr = lane & 15, lk = (lane >> 4) * 8;

  for (int kp = 0; kp < 3 * K; kp += 32) {
    const int ca = (kp < 2 * K) ? kp : kp - 2 * K;  // A col base (hi|lo|hi)
    const int cb = (kp < K) ? kp : kp - K;          // B col base (hi|hi|lo)
    gload16(gA + ca, lA);
    gload16(gA + ca + rstep, lA2);
    gload16(gB + cb, lB);
    gload16(gB + cb + rstep, lB2);
    __syncthreads();

    bs8 af[4], bf[4];
    #pragma unroll
    for (int m = 0; m < 4; ++m)
      af[m] = *(const bs8*)&As[(wr * 64 + m * 16 + lr) * 32 + lk];
    #pragma unroll
    for (int n = 0; n < 4; ++n)
      bf[n] = *(const bs8*)&Bs[(wc * 64 + n * 16 + lr) * 32 + lk];
    #pragma unroll
    for (int m = 0; m < 4; ++m)
      #pragma unroll
      for (int n = 0; n < 4; ++n)
        acc[m][n] = __builtin_amdgcn_mfma_f32_16x16x32_bf16(af[m], bf[n], acc[m][n], 0, 0, 0);
    __syncthreads();
  }

  const int lg = lane >> 4;
  #pragma unroll
  for (int m = 0; m < 4; ++m)
    #pragma unroll
    for (int n = 0; n < 4; ++n) {
      const int col = bn + wc * 64 + n * 16 + lr;
      #pragma unroll
      for (int r = 0; r < 4; ++r) {
        const int row = bm + wr * 64 + m * 16 + lg * 4 + r;
        C[(size_t)row * N + col] = acc[m][n][r];
      }
    }
}

// ---------------------------------------------------------------------------
// Fused RMSNorm + RoPE. Q rows: in-place fp32. K rows: hi/lo bf16 overlay.
// ---------------------------------------------------------------------------
__global__ __launch_bounds__(64) void rmsrope(
    float* __restrict__ qkv, const float* __restrict__ qw,
    const float* __restrict__ kw, const int* __restrict__ pos_ids)
{
  const int row  = blockIdx.x;
  const int lane = threadIdx.x;
  constexpr int NQROWS = M_ * H_;
  const bool isq = row < NQROWS;

  int token; float* ptr; const float* w;
  if (isq) {
    token = row / H_;
    ptr = qkv + (size_t)token * NQKV_ + (row % H_) * HD_;
    w = qw;
  } else {
    const int rk = row - NQROWS;
    token = rk / HKV_;
    ptr = qkv + (size_t)token * NQKV_ + 2048 + (rk % HKV_) * HD_;
    w = kw;
  }

  const float x1 = ptr[lane];
  const float x2 = ptr[lane + 64];
  float ss = x1 * x1 + x2 * x2;
  #pragma unroll
  for (int m = 1; m < 64; m <<= 1) ss += __shfl_xor(ss, m, 64);
  const float rinv = rsqrtf(ss * (1.0f / 128.0f) + 1e-6f);
  const float y1 = x1 * rinv * w[lane];
  const float y2 = x2 * rinv * w[lane + 64];

  const int pos = pos_ids[token];
  const float f = (float)pos * powf(10000.0f, -(float)lane * (1.0f / 64.0f));
  float sn, c;
  sincosf(f, &sn, &c);
  const float o1 = y1 * c - y2 * sn;
  const float o2 = y2 * c + y1 * sn;

  if (isq) {
    ptr[lane]      = o1;
    ptr[lane + 64] = o2;
  } else {
    short* srow = (short*)ptr;
    short h1, l1, h2, l2;
    split2(o1, h1, l1);
    split2(o2, h2, l2);
    srow[lane]       = h1;  srow[lane + 64]  = h2;   // hi[0..127]
    srow[128 + lane] = l1;  srow[192 + lane] = l2;   // lo[0..127]
  }
}

// ---------------------------------------------------------------------------
// V transpose+cast: qkv V region -> Vsp[(b*HKV+kvh)*128 + d][s] bf16 (ld = S)
// ---------------------------------------------------------------------------
__global__ __launch_bounds__(256) void vtrans(
    const float* __restrict__ qkv, short* __restrict__ vsp)
{
  __shared__ float tile[32][33];
  const int by = blockIdx.y;
  const int b = by >> 4, kvh = (by >> 2) & 3, d0 = (by & 3) * 32;
  const int s0 = blockIdx.x * 32;
  const int tx = threadIdx.x, ty = threadIdx.y;
  #pragma unroll
  for (int i = 0; i < 4; ++i)
    tile[ty + 8 * i][tx] =
        qkv[(size_t)(b * S_ + s0 + ty + 8 * i) * NQKV_ + 2560 + kvh * 128 + d0 + tx];
  __syncthreads();
  #pragma unroll
  for (int i = 0; i < 4; ++i) {
    const int d = d0 + ty + 8 * i;
    __hip_bfloat16 v = __float2bfloat16(tile[tx][ty + 8 * i]);
    vsp[((size_t)(b * HKV_ + kvh) * 128 + d) * (size_t)S_ + s0 + tx] = *(short*)&v;
  }
}

// ---------------------------------------------------------------------------
// MFMA causal GQA flash attention v3.
// Block = 4 waves (256 thr), TWO fold-paired 64-row Q tiles {p, 31-p}
//   -> 33 K-tiles per block; grid 16x32 = 512 blocks = 2/CU (TLP!), balanced.
// Wave owns 16 Q-rows. K/V single-buffered in 56KB LDS (2 blocks/CU);
// next tile prefetched into REGISTERS during compute (T14 async-stage split),
// ds_written (XOR-swizzled at write) between two barriers after compute.
// ---------------------------------------------------------------------------
__global__ __launch_bounds__(256, 2) void attn_mfma3(
    const float* __restrict__ qkv, const short* __restrict__ vsp,
    short* __restrict__ osp)
{
  __shared__ __align__(16) short Kh[64 * 128];
  __shared__ __align__(16) short Kl[64 * 128];
  __shared__ __align__(16) short Vt[128 * 64];   // [d][j]
  __shared__ __align__(16) short sP[64 * 64];    // [r][j], wave-private rows

  const int t    = threadIdx.x;
  const int lane = t & 63;
  const int w    = t >> 6;        // wave id: rows 16w..16w+15
  const int lr   = lane & 15;
  const int g    = lane >> 4;
  const int p  = blockIdx.x;      // fold pair index 0..15
  const int bh = blockIdx.y;
  const int b = bh >> 4, h = bh & 15;
  const int kvh = h >> 2;
  const int bhk = b * HKV_ + kvh;
  const short* kb = (const short*)qkv;   // K region overlaid bf16 by rmsrope

  // staging registers (12 x b128 per thread per tile)
  bs8 rKh[4], rKl[4], rV[4];

  const short* kbase = kb + (size_t)b * S_ * 6144 + 4096 + kvh * 256;
  const short* vbase = vsp + (size_t)bhk * 128 * (size_t)S_;

  auto stage_load = [&](int k0) {
    #pragma unroll
    for (int i = 0; i < 4; ++i) {
      const int idx = t + 256 * i;
      const int sj = idx >> 4, c = idx & 15;
      rKh[i] = *(const bs8*)(kbase + (size_t)(k0 + sj) * 6144 + 8 * c);
      rKl[i] = *(const bs8*)(kbase + (size_t)(k0 + sj) * 6144 + 128 + 8 * c);
      const int d = idx >> 3, c2 = idx & 7;
      rV[i] = *(const bs8*)(vbase + (size_t)d * S_ + k0 + 8 * c2);
    }
  };
  auto stage_write = [&]() {
    #pragma unroll
    for (int i = 0; i < 4; ++i) {
      const int idx = t + 256 * i;
      const int sj = idx >> 4, c = idx & 15;
      *(bs8*)&Kh[sj * 128 + ((c ^ (sj & 15)) << 3)] = rKh[i];
      *(bs8*)&Kl[sj * 128 + ((c ^ (sj & 15)) << 3)] = rKl[i];
      const int d = idx >> 3, c2 = idx & 7;
      *(bs8*)&Vt[d * 64 + ((c2 ^ (d & 7)) << 3)] = rV[i];
    }
  };

  const int qts[2] = {p, 31 - p};

  #pragma unroll 1
  for (int sg = 0; sg < 2; ++sg) {
    const int qt  = qts[sg];
    const int q0  = 64 * qt;
    const int ntk = qt + 1;

    stage_load(0);   // tile 0 -> regs (in flight while Q loads/splits)

    // ---- Q fragments: rows 16w+lr, k-chunks g*8 + 32*dc ----
    bs8 qh[4], ql[4];
    {
      const float* qrow =
          qkv + (size_t)(b * S_ + q0 + 16 * w + lr) * NQKV_ + h * HD_ + g * 8;
      #pragma unroll
      for (int dc = 0; dc < 4; ++dc) {
        float x[8];
        *(float4*)&x[0] = *(const float4*)(qrow + 32 * dc);
        *(float4*)&x[4] = *(const float4*)(qrow + 32 * dc + 4);
        #pragma unroll
        for (int e = 0; e < 8; ++e) {
          short hi, lo;
          split2(x[e] * QSCALE, hi, lo);
          qh[dc][e] = hi; ql[dc][e] = lo;
        }
      }
    }

    fx4 o[8] = {};
    float m_i[4] = {-1e30f, -1e30f, -1e30f, -1e30f};
    float l_i[4] = {0.f, 0.f, 0.f, 0.f};

    stage_write();        // compiler inserts vmcnt wait for rK*/rV
    __syncthreads();      // tile 0 visible
    if (ntk > 1) stage_load(64);   // tile 1 loads fly during tile 0 compute

    #pragma unroll 1
    for (int kt = 0; kt < ntk; ++kt) {
      const int k0 = 64 * kt;

      // ---- S = Q K^T (3-term split, fp32 accum) ----
      fx4 s[4] = {};
      __builtin_amdgcn_s_setprio(1);
      #pragma unroll
      for (int dc = 0; dc < 4; ++dc) {
        #pragma unroll
        for (int n = 0; n < 4; ++n) {
          const int ko = (16 * n + lr) * 128 + (((dc * 4 + g) ^ lr) << 3);
          const bs8 fh = *(const bs8*)&Kh[ko];
          const bs8 fl = *(const bs8*)&Kl[ko];
          s[n] = __builtin_amdgcn_mfma_f32_16x16x32_bf16(qh[dc], fh, s[n], 0, 0, 0);
          s[n] = __builtin_amdgcn_mfma_f32_16x16x32_bf16(ql[dc], fh, s[n], 0, 0, 0);
          s[n] = __builtin_amdgcn_mfma_f32_16x16x32_bf16(qh[dc], fl, s[n], 0, 0, 0);
        }
      }
      __builtin_amdgcn_s_setprio(0);

      if (kt == qt) {   // diagonal tile: causal mask
        #pragma unroll
        for (int n = 0; n < 4; ++n)
          #pragma unroll
          for (int r = 0; r < 4; ++r)
            if (16 * n + lr > 16 * w + 4 * g + r) s[n][r] = -1e30f;
      }

      // ---- online softmax (rows 16w+4g+r) + P -> sP (wave-private rows) ----
      #pragma unroll
      for (int r = 0; r < 4; ++r) {
        float rm = fmaxf(fmaxf(s[0][r], s[1][r]), fmaxf(s[2][r], s[3][r]));
        rm = fmaxf(rm, __shfl_xor(rm, 1, 64));
        rm = fmaxf(rm, __shfl_xor(rm, 2, 64));
        rm = fmaxf(rm, __shfl_xor(rm, 4, 64));
        rm = fmaxf(rm, __shfl_xor(rm, 8, 64));
        const float mn    = fmaxf(m_i[r], rm);
        const float alpha = __expf(m_i[r] - mn);
        float ps = 0.f;
        #pragma unroll
        for (int n = 0; n < 4; ++n) {
          const float pv = __expf(s[n][r] - mn);
          s[n][r] = pv;
          ps += pv;
        }
        ps += __shfl_xor(ps, 1, 64);
        ps += __shfl_xor(ps, 2, 64);
        ps += __shfl_xor(ps, 4, 64);
        ps += __shfl_xor(ps, 8, 64);
        l_i[r] = l_i[r] * alpha + ps;
        m_i[r] = mn;
        #pragma unroll
        for (int df = 0; df < 8; ++df) o[df][r] *= alpha;

        const int rr = 16 * w + 4 * g + r;
        #pragma unroll
        for (int n = 0; n < 4; ++n) {
          __hip_bfloat16 pb = __float2bfloat16(s[n][r]);
          sP[rr * 64 + ((((2 * n + (lr >> 3)) ^ (rr & 7))) << 3) + (lr & 7)] = *(short*)&pb;
        }
      }

      // ---- PV accumulate ----
      const int pro = (16 * w + lr) * 64;
      const bs8 pa0 = *(const bs8*)&sP[pro + (((g)     ^ (lr & 7)) << 3)];
      const bs8 pa1 = *(const bs8*)&sP[pro + (((g + 4) ^ (lr & 7)) << 3)];
      __builtin_amdgcn_s_setprio(1);
      #pragma unroll
      for (int df = 0; df < 8; ++df) {
        const int vo = (16 * df + lr) * 64;
        const bs8 v0 = *(const bs8*)&Vt[vo + (((g)     ^ (lr & 7)) << 3)];
        const bs8 v1 = *(const bs8*)&Vt[vo + (((g + 4) ^ (lr & 7)) << 3)];
        o[df] = __builtin_amdgcn_mfma_f32_16x16x32_bf16(pa0, v0, o[df], 0, 0, 0);
        o[df] = __builtin_amdgcn_mfma_f32_16x16x32_bf16(pa1, v1, o[df], 0, 0, 0);
      }
      __builtin_amdgcn_s_setprio(0);

      __syncthreads();             // A: all waves done reading K/V LDS
      if (kt + 1 < ntk) {
        stage_write();             // write tile kt+1 (vmcnt wait auto)
        __syncthreads();           // B: tile kt+1 visible
        if (kt + 2 < ntk) stage_load(64 * (kt + 2));
      }
    }

    // ---- normalize + hi/lo split write for WO GEMM ----
    #pragma unroll
    for (int r = 0; r < 4; ++r) {
      const float inv = 1.0f / l_i[r];
      const size_t ro =
          (size_t)(b * S_ + q0 + 16 * w + 4 * g + r) * 4096 + h * HD_;
      #pragma unroll
      for (int df = 0; df < 8; ++df) {
        short hi, lo;
        split2(o[df][r] * inv, hi, lo);
        osp[ro + 16 * df + lr]        = hi;
        osp[ro + 2048 + 16 * df + lr] = lo;
      }
    }
  }
}

// ---------------------------------------------------------------------------
extern "C" void kernel_launch(void* const* d_in, const int* in_sizes, int n_in,
                              void* d_out, int out_size, void* d_ws, size_t ws_size,
                              hipStream_t stream) {
  const float* hidden = (const float*)d_in[0];
  const float* wq     = (const float*)d_in[1];
  const float* wk     = (const float*)d_in[2];
  const float* wv     = (const float*)d_in[3];
  const float* wo     = (const float*)d_in[4];
  const float* qw     = (const float*)d_in[5];
  const float* kw     = (const float*)d_in[6];
  const int*   pos    = (const int*)d_in[7];
  float*       out    = (float*)d_out;

  // Workspace (104 MB):
  //   R0 [0,32MB): Asp hidden split; reused as Osp (attn-out split)
  //   R1 [32,56MB): Bsp weight splits; rows 2048.. reused as Vsp after QKV GEMM
  //   R2 [56,104MB): qkv fp32 (K region overlaid bf16 hi/lo by rmsrope)
  const size_t aspB = (size_t)M_ * 4096 * 2;
  const size_t bspB = (size_t)NQKV_ * 4096 * 2;
  const size_t qkvB = (size_t)M_ * NQKV_ * 4;
  if (ws_size < aspB + bspB + qkvB) return;   // visible failure

  short* Asp = (short*)d_ws;
  short* Bsp = (short*)((char*)d_ws + aspB);
  float* qkv = (float*)((char*)d_ws + aspB + bspB);
  short* Osp = Asp;
  short* Vsp = Bsp + (size_t)2048 * 4096;   // 4MB inside dead QKV-weight rows

  // 1) precision splits
  split_hidden<<<(M_ * D_ / 4) / 256, 256, 0, stream>>>((const float4*)hidden, Asp);
  tsplit<<<dim3(2048 / 32, 64), dim3(32, 8), 0, stream>>>(wq, 2048, Bsp, 0);
  tsplit<<<dim3(512 / 32, 64),  dim3(32, 8), 0, stream>>>(wk, 512,  Bsp, 2048);
  tsplit<<<dim3(512 / 32, 64),  dim3(32, 8), 0, stream>>>(wv, 512,  Bsp, 2560);

  // 2) fused QKV projection
  gemm_split_bf16<<<dim3(NQKV_ / 128, M_ / 128), 256, 0, stream>>>(
      Asp, Bsp, qkv, M_, NQKV_, 2048);

  // 3) RMSNorm + RoPE (Q fp32 in place; K -> bf16 hi/lo in place)
  rmsrope<<<M_ * (H_ + HKV_), 64, 0, stream>>>(qkv, qw, kw, pos);

  // 4) V transpose+cast into Vsp
  vtrans<<<dim3(S_ / 32, 32), dim3(32, 8), 0, stream>>>(qkv, Vsp);

  // 5) MFMA flash attention v3 -> Osp (hi/lo split, ld 4096)
  attn_mfma3<<<dim3(16, B_ * H_), 256, 0, stream>>>(qkv, Vsp, Osp);

  // 6) output projection
  tsplit<<<dim3(2048 / 32, 64), dim3(32, 8), 0, stream>>>(wo, 2048, Bsp, 0);
  gemm_split_bf16<<<dim3(D_ / 128, M_ / 128), 256, 0, stream>>>(
      Osp, Bsp, out, M_, D_, 2048);
}